// Round 17
// baseline (415.806 us; speedup 1.0000x reference)
//
#include <hip/hip_runtime.h>
#include <hip/hip_bf16.h>
#include <math.h>
#include <stdint.h>

#define LSEQ 1024
#define DMODEL 768
#define DINNER 1536
#define DSTATE 16
#define DRANK 48
#define KCONV 4
#define NLAYER 2
#define DBC 80  // DRANK + 2*DSTATE
#define NQ 8            // L-split for the 3-phase scan
#define QL (LSEQ / NQ)  // 128
#define SCH 8           // chunks per scan block
#define SCW 32          // channels per scan block (32*2B = full 64B line)
#define QCH (QL / SCH)  // 16 steps per chunk

typedef unsigned short u16;
typedef __attribute__((ext_vector_type(8))) __bf16 bf16x8;
typedef __attribute__((ext_vector_type(4))) float f32x4;
typedef __attribute__((ext_vector_type(4))) unsigned short us4;  // 4 u16 = 8 B
typedef __attribute__((ext_vector_type(8))) unsigned short us8;  // 8 u16 = 16 B

__device__ __forceinline__ u16 f2bf(float f) {
  union { float f; unsigned u; } v; v.f = f;
  unsigned r = v.u + 0x7fffu + ((v.u >> 16) & 1u);  // RNE
  return (u16)(r >> 16);
}
__device__ __forceinline__ float bf2f(u16 u) {
  union { unsigned u; float f; } v; v.u = ((unsigned)u) << 16;
  return v.f;
}

// CK-style addrspace casts for global_load_lds (direct HBM->LDS DMA, 16B/lane)
__device__ __forceinline__ void gload16(const void* g, void* l) {
  auto gp = reinterpret_cast<const __attribute__((address_space(1))) uint32_t*>(
      reinterpret_cast<uintptr_t>(g));
  auto lp = reinterpret_cast<__attribute__((address_space(3))) uint32_t*>(
      reinterpret_cast<uintptr_t>(l));
  __builtin_amdgcn_global_load_lds(gp, lp, 16, 0, 0);
}

// ------------- fused fp32 -> bf16 convert of 4 weight mats, BOTH layers ------
#define CV0 589824              // 3072*768/4
#define CV1 (CV0 + 1179648)     // +1536*3072/4
#define CV2 (CV1 + 393216)      // +1024*1536/4
#define CV3 (CV2 + 294912)      // +768*1536/4 = 2457600 total float4s
#define WBL 12189696            // per-layer bf16 weight region (u16 elems)
__global__ __launch_bounds__(256) void cvt4_k(
    const float* __restrict__ i0, u16* __restrict__ o0, int s0o,
    const float* __restrict__ i1, u16* __restrict__ o1, int s1o,
    const float* __restrict__ i2, u16* __restrict__ o2, int s2o,
    const float* __restrict__ i3, u16* __restrict__ o3, int s3o) {
  int i = blockIdx.x * 256 + threadIdx.x;
  int lay = blockIdx.y;
  const float* in; u16* out; int off;
  if (i < CV0)      { in = i0 + (size_t)lay * s0o * 4; out = o0 + (size_t)lay * WBL; off = i; }
  else if (i < CV1) { in = i1 + (size_t)lay * s1o * 4; out = o1 + (size_t)lay * WBL; off = i - CV0; }
  else if (i < CV2) { in = i2 + (size_t)lay * s2o * 4; out = o2 + (size_t)lay * WBL; off = i - CV1; }
  else              { in = i3 + (size_t)lay * s3o * 4; out = o3 + (size_t)lay * WBL; off = i - CV2; }
  float4 v = ((const float4*)in)[off];
  us4 o; o[0] = f2bf(v.x); o[1] = f2bf(v.y); o[2] = f2bf(v.z); o[3] = f2bf(v.w);
  ((us4*)out)[off] = o;
}

// ---------------- fp32 -> bf16 transpose-convert (both layers via z) ---------
__global__ __launch_bounds__(256) void transcvt_k(const float* __restrict__ in0,
                                                  u16* __restrict__ out0,
                                                  int R, int C) {
  __shared__ float t[32][33];
  const float* in = in0 + (size_t)blockIdx.z * R * C;
  u16* out = out0 + (size_t)blockIdx.z * WBL;
  int c0 = blockIdx.x * 32, r0 = blockIdx.y * 32;
  int tx = threadIdx.x & 31, ty = threadIdx.x >> 5;
  for (int i = ty; i < 32; i += 8) t[i][tx] = in[(size_t)(r0 + i) * C + c0 + tx];
  __syncthreads();
  for (int i = ty; i < 32; i += 8)
    out[(size_t)(c0 + i) * R + r0 + tx] = f2bf(t[tx][i]);
}

// ---------------- rmsnorm (bf16 out) ----------------
__global__ __launch_bounds__(256) void rmsnorm_k(const float* __restrict__ x,
                                                 const float* __restrict__ w,
                                                 u16* __restrict__ xn) {
  int row = blockIdx.x;
  int tid = threadIdx.x;
  const float* xr = x + (size_t)row * DMODEL;
  float ss = 0.f;
  for (int j = tid; j < DMODEL; j += 256) { float v = xr[j]; ss += v * v; }
  __shared__ float red[256];
  red[tid] = ss; __syncthreads();
  for (int s = 128; s > 0; s >>= 1) { if (tid < s) red[tid] += red[tid + s]; __syncthreads(); }
  float scale = rsqrtf(red[0] / (float)DMODEL + 1e-5f);
  u16* outr = xn + (size_t)row * DMODEL;
  for (int j = tid; j < DMODEL; j += 256) outr[j] = f2bf(xr[j] * scale * w[j]);
}

// ---------------- MFMA bf16 GEMM: 64x64 tile (kept for out GEMM) -------------
// EPI bit0: +bias; bit2: +resid fp32; bit3: bf16 out; bit4: *silu(resid);
// bit5: resid is bf16.
template<int EPI>
__global__ __launch_bounds__(256) void mgemm_k(
    const u16* __restrict__ A, int lda,
    const u16* __restrict__ B, int ldb,
    void* __restrict__ Cv, int ldc, int K,
    const float* __restrict__ bias,
    const float* __restrict__ resid, int ldr)
{
  __shared__ u16 As[2][64 * 64];
  __shared__ u16 Bs[2][64 * 64];
  const int tid = threadIdx.x;
  const int lane = tid & 63;
  const int w = tid >> 6;

  const int nbx = gridDim.x;
  int bid = blockIdx.y * nbx + blockIdx.x;
  const int nwg = nbx * gridDim.y;
  bid = (bid & 7) * (nwg >> 3) + (bid >> 3);
  const int bm = (bid / nbx) * 64;
  const int bn = (bid % nbx) * 64;

  const int srow = lane >> 3;
  const int scs = (lane & 7) ^ srow;
  const int gA = 2 * w;
  const u16* Asrc0 = A + (size_t)(bm + gA * 8 + srow) * lda + scs * 8;
  const u16* Asrc1 = Asrc0 + (size_t)8 * lda;
  const u16* Bsrc0 = B + (size_t)(bn + gA * 8 + srow) * ldb + scs * 8;
  const u16* Bsrc1 = Bsrc0 + (size_t)8 * ldb;
  const int d0 = gA * 512;
  const int d1 = d0 + 512;

  const int fr = lane & 15;
  const int fs = lane >> 4;
  const int wm = (w >> 1) * 32;
  const int wn = (w & 1) * 32;
  int aoff[2][2], boff[2][2];
#pragma unroll
  for (int i = 0; i < 2; i++)
#pragma unroll
    for (int h = 0; h < 2; h++) {
      const int g = h * 4 + fs;
      aoff[i][h] = (wm + i * 16 + fr) * 64 + (g ^ (fr & 7)) * 8;
      boff[i][h] = (wn + i * 16 + fr) * 64 + (g ^ (fr & 7)) * 8;
    }

  f32x4 acc[2][2];
#pragma unroll
  for (int i = 0; i < 2; i++)
#pragma unroll
    for (int j = 0; j < 2; j++) acc[i][j] = (f32x4){0.f, 0.f, 0.f, 0.f};

#define STAGE(buf, k0) do { \
    gload16(Asrc0 + (k0), &As[buf][d0]); \
    gload16(Asrc1 + (k0), &As[buf][d1]); \
    gload16(Bsrc0 + (k0), &Bs[buf][d0]); \
    gload16(Bsrc1 + (k0), &Bs[buf][d1]); \
  } while (0)

  const int nk = K >> 6;
  STAGE(0, 0);

  for (int t = 0; t < nk; t++) {
    const int buf = t & 1;
    __syncthreads();
    if (t + 1 < nk) STAGE(buf ^ 1, (t + 1) << 6);
    const u16* As_ = As[buf];
    const u16* Bs_ = Bs[buf];
#pragma unroll
    for (int h = 0; h < 2; h++) {
      bf16x8 a0 = *reinterpret_cast<const bf16x8*>(As_ + aoff[0][h]);
      bf16x8 a1 = *reinterpret_cast<const bf16x8*>(As_ + aoff[1][h]);
      bf16x8 b0 = *reinterpret_cast<const bf16x8*>(Bs_ + boff[0][h]);
      bf16x8 b1 = *reinterpret_cast<const bf16x8*>(Bs_ + boff[1][h]);
      acc[0][0] = __builtin_amdgcn_mfma_f32_16x16x32_bf16(a0, b0, acc[0][0], 0, 0, 0);
      acc[0][1] = __builtin_amdgcn_mfma_f32_16x16x32_bf16(a0, b1, acc[0][1], 0, 0, 0);
      acc[1][0] = __builtin_amdgcn_mfma_f32_16x16x32_bf16(a1, b0, acc[1][0], 0, 0, 0);
      acc[1][1] = __builtin_amdgcn_mfma_f32_16x16x32_bf16(a1, b1, acc[1][1], 0, 0, 0);
    }
  }
#undef STAGE

#pragma unroll
  for (int i = 0; i < 2; i++) {
#pragma unroll
    for (int j = 0; j < 2; j++) {
      const int col = bn + wn + j * 16 + fr;
      const int row0 = bm + wm + i * 16 + fs * 4;
      float bv = (EPI & 1) ? bias[col] : 0.f;
#pragma unroll
      for (int r = 0; r < 4; r++) {
        float v = acc[i][j][r] + bv;
        if (EPI & 4) v += resid[(size_t)(row0 + r) * ldr + col];
        if (EPI & 16) {
          float z = (EPI & 32)
              ? bf2f(((const u16*)resid)[(size_t)(row0 + r) * ldr + col])
              : resid[(size_t)(row0 + r) * ldr + col];
          v *= z / (1.f + __expf(-z));
        }
        if (EPI & 8) ((u16*)Cv)[(size_t)(row0 + r) * ldc + col] = f2bf(v);
        else         ((float*)Cv)[(size_t)(row0 + r) * ldc + col] = v;
      }
    }
  }
}

// ------- MFMA bf16 GEMM: 64x128 tile, 4 waves each 32x64 (2x4 frags) ---------
template<int EPI>
__global__ __launch_bounds__(256) void mgemmW_k(
    const u16* __restrict__ A, int lda,
    const u16* __restrict__ B, int ldb,
    void* __restrict__ Cv, int ldc, int K,
    const float* __restrict__ bias,
    const float* __restrict__ resid, int ldr)
{
  __shared__ u16 As[2][64 * 64];
  __shared__ u16 Bs[2][128 * 64];
  const int tid = threadIdx.x;
  const int lane = tid & 63;
  const int w = tid >> 6;

  const int nbx = gridDim.x;
  int bid = blockIdx.y * nbx + blockIdx.x;
  const int nwg = nbx * gridDim.y;
  bid = (bid & 7) * (nwg >> 3) + (bid >> 3);
  const int bm = (bid / nbx) * 64;
  const int bn = (bid % nbx) * 128;

  const int srow = lane >> 3;
  const int scs = (lane & 7) ^ srow;
  const u16* Asrc0 = A + (size_t)(bm + (2 * w) * 8 + srow) * lda + scs * 8;
  const u16* Asrc1 = Asrc0 + (size_t)8 * lda;
  const int da0 = (2 * w) * 512, da1 = da0 + 512;
  const u16* Bsrc0 = B + (size_t)(bn + (4 * w) * 8 + srow) * ldb + scs * 8;
  const u16* Bsrc1 = Bsrc0 + (size_t)8 * ldb;
  const u16* Bsrc2 = Bsrc1 + (size_t)8 * ldb;
  const u16* Bsrc3 = Bsrc2 + (size_t)8 * ldb;
  const int db0 = (4 * w) * 512;

  const int fr = lane & 15;
  const int fs = lane >> 4;
  const int wm = (w >> 1) * 32;
  const int wn = (w & 1) * 64;
  int aoff[2][2], boff[4][2];
#pragma unroll
  for (int h = 0; h < 2; h++) {
    const int g = h * 4 + fs;
    const int sw = (g ^ (fr & 7)) * 8;
#pragma unroll
    for (int i = 0; i < 2; i++) aoff[i][h] = (wm + i * 16 + fr) * 64 + sw;
#pragma unroll
    for (int j = 0; j < 4; j++) boff[j][h] = (wn + j * 16 + fr) * 64 + sw;
  }

  f32x4 acc[2][4];
#pragma unroll
  for (int i = 0; i < 2; i++)
#pragma unroll
    for (int j = 0; j < 4; j++) acc[i][j] = (f32x4){0.f, 0.f, 0.f, 0.f};

#define STAGEW(buf, k0) do { \
    gload16(Asrc0 + (k0), &As[buf][da0]); \
    gload16(Asrc1 + (k0), &As[buf][da1]); \
    gload16(Bsrc0 + (k0), &Bs[buf][db0]); \
    gload16(Bsrc1 + (k0), &Bs[buf][db0 + 512]); \
    gload16(Bsrc2 + (k0), &Bs[buf][db0 + 1024]); \
    gload16(Bsrc3 + (k0), &Bs[buf][db0 + 1536]); \
  } while (0)

  const int nk = K >> 6;
  STAGEW(0, 0);

  for (int t = 0; t < nk; t++) {
    const int buf = t & 1;
    __syncthreads();
    if (t + 1 < nk) STAGEW(buf ^ 1, (t + 1) << 6);
    const u16* As_ = As[buf];
    const u16* Bs_ = Bs[buf];
#pragma unroll
    for (int h = 0; h < 2; h++) {
      bf16x8 a0 = *reinterpret_cast<const bf16x8*>(As_ + aoff[0][h]);
      bf16x8 a1 = *reinterpret_cast<const bf16x8*>(As_ + aoff[1][h]);
#pragma unroll
      for (int j = 0; j < 4; j++) {
        bf16x8 b = *reinterpret_cast<const bf16x8*>(Bs_ + boff[j][h]);
        acc[0][j] = __builtin_amdgcn_mfma_f32_16x16x32_bf16(a0, b, acc[0][j], 0, 0, 0);
        acc[1][j] = __builtin_amdgcn_mfma_f32_16x16x32_bf16(a1, b, acc[1][j], 0, 0, 0);
      }
    }
  }
#undef STAGEW

#pragma unroll
  for (int i = 0; i < 2; i++) {
#pragma unroll
    for (int j = 0; j < 4; j++) {
      const int col = bn + wn + j * 16 + fr;
      const int row0 = bm + wm + i * 16 + fs * 4;
      float bv = (EPI & 1) ? bias[col] : 0.f;
#pragma unroll
      for (int r = 0; r < 4; r++) {
        float v = acc[i][j][r] + bv;
        if (EPI & 4) v += resid[(size_t)(row0 + r) * ldr + col];
        if (EPI & 16) {
          float z = (EPI & 32)
              ? bf2f(((const u16*)resid)[(size_t)(row0 + r) * ldr + col])
              : resid[(size_t)(row0 + r) * ldr + col];
          v *= z / (1.f + __expf(-z));
        }
        if (EPI & 8) ((u16*)Cv)[(size_t)(row0 + r) * ldc + col] = f2bf(v);
        else         ((float*)Cv)[(size_t)(row0 + r) * ldc + col] = v;
      }
    }
  }
}

// ---------------- fused S + vv GEMM; vv part writes vvT directly -------------
__global__ __launch_bounds__(256) void svgemm_k(
    const u16* __restrict__ wA, const u16* __restrict__ ypro,
    const u16* __restrict__ wVT,
    float* __restrict__ Smat, u16* __restrict__ vvT)
{
  __shared__ u16 As[2][64 * 64];
  __shared__ u16 Bs[2][64 * 64];
  __shared__ u16 tr[4][32][33];
  const int tid = threadIdx.x;
  const int lane = tid & 63;
  const int w = tid >> 6;

  int bid = blockIdx.x;
  bid = (bid & 7) * 80 + (bid >> 3);
  const bool is_s = bid < 256;
  const u16* A;
  const u16* B;
  int bm, bn;
  if (is_s) { A = wA;   B = ypro; bm = (bid >> 4) * 64;         bn = (bid & 15) * 64; }
  else      { A = ypro; B = wVT;  bm = ((bid - 256) / 24) * 64; bn = ((bid - 256) % 24) * 64; }

  const int srow = lane >> 3;
  const int scs = (lane & 7) ^ srow;
  const int gA = 2 * w;
  const u16* Asrc0 = A + (size_t)(bm + gA * 8 + srow) * DINNER + scs * 8;
  const u16* Asrc1 = Asrc0 + (size_t)8 * DINNER;
  const u16* Bsrc0 = B + (size_t)(bn + gA * 8 + srow) * DINNER + scs * 8;
  const u16* Bsrc1 = Bsrc0 + (size_t)8 * DINNER;
  const int d0 = gA * 512;
  const int d1 = d0 + 512;

  const int fr = lane & 15;
  const int fs = lane >> 4;
  const int wm = (w >> 1) * 32;
  const int wn = (w & 1) * 32;
  int aoff[2][2], boff[2][2];
#pragma unroll
  for (int i = 0; i < 2; i++)
#pragma unroll
    for (int h = 0; h < 2; h++) {
      const int g = h * 4 + fs;
      aoff[i][h] = (wm + i * 16 + fr) * 64 + (g ^ (fr & 7)) * 8;
      boff[i][h] = (wn + i * 16 + fr) * 64 + (g ^ (fr & 7)) * 8;
    }

  f32x4 acc[2][2];
#pragma unroll
  for (int i = 0; i < 2; i++)
#pragma unroll
    for (int j = 0; j < 2; j++) acc[i][j] = (f32x4){0.f, 0.f, 0.f, 0.f};

#define STAGE(buf, k0) do { \
    gload16(Asrc0 + (k0), &As[buf][d0]); \
    gload16(Asrc1 + (k0), &As[buf][d1]); \
    gload16(Bsrc0 + (k0), &Bs[buf][d0]); \
    gload16(Bsrc1 + (k0), &Bs[buf][d1]); \
  } while (0)

  STAGE(0, 0);
  for (int t = 0; t < DINNER / 64; t++) {
    const int buf = t & 1;
    __syncthreads();
    if (t + 1 < DINNER / 64) STAGE(buf ^ 1, (t + 1) << 6);
    const u16* As_ = As[buf];
    const u16* Bs_ = Bs[buf];
#pragma unroll
    for (int h = 0; h < 2; h++) {
      bf16x8 a0 = *reinterpret_cast<const bf16x8*>(As_ + aoff[0][h]);
      bf16x8 a1 = *reinterpret_cast<const bf16x8*>(As_ + aoff[1][h]);
      bf16x8 b0 = *reinterpret_cast<const bf16x8*>(Bs_ + boff[0][h]);
      bf16x8 b1 = *reinterpret_cast<const bf16x8*>(Bs_ + boff[1][h]);
      acc[0][0] = __builtin_amdgcn_mfma_f32_16x16x32_bf16(a0, b0, acc[0][0], 0, 0, 0);
      acc[0][1] = __builtin_amdgcn_mfma_f32_16x16x32_bf16(a0, b1, acc[0][1], 0, 0, 0);
      acc[1][0] = __builtin_amdgcn_mfma_f32_16x16x32_bf16(a1, b0, acc[1][0], 0, 0, 0);
      acc[1][1] = __builtin_amdgcn_mfma_f32_16x16x32_bf16(a1, b1, acc[1][1], 0, 0, 0);
    }
  }
#undef STAGE

  if (is_s) {
#pragma unroll
    for (int i = 0; i < 2; i++)
#pragma unroll
      for (int j = 0; j < 2; j++) {
        const int col = bn + wn + j * 16 + fr;
        const int row0 = bm + wm + i * 16 + fs * 4;
#pragma unroll
        for (int r = 0; r < 4; r++)
          Smat[(size_t)(row0 + r) * LSEQ + col] = acc[i][j][r];
      }
  } else {
#pragma unroll
    for (int i = 0; i < 2; i++)
#pragma unroll
      for (int j = 0; j < 2; j++) {
        const int lr0 = i * 16 + fs * 4;
        const int lc = j * 16 + fr;
#pragma unroll
        for (int r = 0; r < 4; r++) tr[w][lr0 + r][lc] = f2bf(acc[i][j][r]);
      }
    __syncthreads();
    const int lc = lane >> 1;
    const int half = lane & 1;
    const int gcol = bn + wn + lc;
    const int grow0 = bm + wm + half * 16;
    u16* dst = vvT + (size_t)gcol * LSEQ + grow0;
#pragma unroll
    for (int q = 0; q < 4; q++) {
      us4 v;
#pragma unroll
      for (int e = 0; e < 4; e++) v[e] = tr[w][half * 16 + q * 4 + e][lc];
      *(us4*)(dst + q * 4) = v;
    }
  }
}

// ---------------- thin dbc GEMM (bf16 A, f+b merged) -------------------------
#define TG_R 16
#define TG_KC 96
#define TG_KS 16

__global__ __launch_bounds__(256) void thin_gemm_k(
    const u16* __restrict__ Af_, const u16* __restrict__ Ab_,
    const float* __restrict__ Bf_, const float* __restrict__ Bb_,
    float* __restrict__ partial)
{
  __shared__ u16 As[TG_R][TG_KC];
  __shared__ float Bs[80][100];
  const u16* A = blockIdx.z ? Ab_ : Af_;
  const float* B = blockIdx.z ? Bb_ : Bf_;
  float* part = partial + (size_t)blockIdx.z * TG_KS * LSEQ * DBC;
  const int tid = threadIdx.x;
  const int m0 = blockIdx.x * TG_R;
  const int ks = blockIdx.y;
  const int k0 = ks * TG_KC;

  for (int i = tid; i < 384; i += 256) {
    int r = i / 24, q = i % 24;
    *(us4*)&As[r][q * 4] = *(const us4*)(A + (size_t)(m0 + r) * DINNER + k0 + q * 4);
  }
  for (int i = tid; i < 1920; i += 256) {
    int r = i / 24, q = i % 24;
    *(float4*)&Bs[r][q * 4] = *(const float4*)(B + (size_t)r * DINNER + k0 + q * 4);
  }
  __syncthreads();

  const int r = tid >> 4;
  const int c0 = (tid & 15) * 5;
  float acc[5] = {};
  for (int k = 0; k < TG_KC; k++) {
    float a = bf2f(As[r][k]);
#pragma unroll
    for (int j = 0; j < 5; j++) acc[j] += a * Bs[c0 + j][k];
  }
  float* out = part + ((size_t)ks * LSEQ + m0 + r) * DBC + c0;
#pragma unroll
  for (int j = 0; j < 5; j++) out[j] = acc[j];
}

__global__ __launch_bounds__(256) void reduce_dbc_k(const float* __restrict__ partial,
                                                    float* __restrict__ outf,
                                                    float* __restrict__ outb) {
  int i = blockIdx.x * 256 + threadIdx.x;
  const float* part = partial + (size_t)blockIdx.y * TG_KS * LSEQ * DBC;
  float s = 0.f;
#pragma unroll
  for (int ks = 0; ks < TG_KS; ks++) s += part[(size_t)ks * (LSEQ * DBC) + i];
  (blockIdx.y ? outb : outf)[i] = s;
}

// ---------------- delta = softplus(dlt @ dt_w^T + dt_b), f+b merged, bf16 out
#define BM 64
#define BN 64
#define BK 16

__global__ __launch_bounds__(256) void delta_gemm_k(
    const float* __restrict__ A0, const float* __restrict__ A1,
    const float* __restrict__ B0, const float* __restrict__ B1,
    const float* __restrict__ b0, const float* __restrict__ b1,
    u16* __restrict__ C0, u16* __restrict__ C1)
{
  __shared__ float Asf[BK][BM];
  __shared__ float Bsf[BK][BN + 4];
  const float* A = blockIdx.z ? A1 : A0;
  const float* B = blockIdx.z ? B1 : B0;
  const float* bias = blockIdx.z ? b1 : b0;
  u16* C = blockIdx.z ? C1 : C0;
  const int tid = threadIdx.x;
  const int bm = blockIdx.y * BM;
  const int bn = blockIdx.x * BN;
  const int ar = tid >> 2;
  const int ak = (tid & 3) << 2;
  const int ty = tid >> 4, tx = tid & 15;
  float acc[4][4] = {};

  for (int k0 = 0; k0 < DRANK; k0 += BK) {
    float4 av = *(const float4*)(A + (size_t)(bm + ar) * DBC + k0 + ak);
    float4 bv = *(const float4*)(B + (size_t)(bn + ar) * DRANK + k0 + ak);
    __syncthreads();
    Asf[ak + 0][ar] = av.x; Asf[ak + 1][ar] = av.y;
    Asf[ak + 2][ar] = av.z; Asf[ak + 3][ar] = av.w;
    Bsf[ak + 0][ar] = bv.x; Bsf[ak + 1][ar] = bv.y;
    Bsf[ak + 2][ar] = bv.z; Bsf[ak + 3][ar] = bv.w;
    __syncthreads();
#pragma unroll
    for (int kk = 0; kk < BK; kk++) {
      float4 a4 = *(const float4*)&Asf[kk][ty * 4];
      float4 b4 = *(const float4*)&Bsf[kk][tx * 4];
      float a[4] = {a4.x, a4.y, a4.z, a4.w};
      float b[4] = {b4.x, b4.y, b4.z, b4.w};
#pragma unroll
      for (int i = 0; i < 4; i++)
#pragma unroll
        for (int j = 0; j < 4; j++)
          acc[i][j] += a[i] * b[j];
    }
  }

#pragma unroll
  for (int i = 0; i < 4; i++) {
    int row = bm + ty * 4 + i;
#pragma unroll
    for (int j = 0; j < 4; j++) {
      int col = bn + tx * 4 + j;
      float v = acc[i][j] + bias[col];
      v = (v > 20.f) ? v : log1pf(__expf(v));
      C[(size_t)row * DINNER + col] = f2bf(v);
    }
  }
}

// ------- causal depthwise conv + silu, 8 channels/thread (bf16 in/out) -------
__global__ __launch_bounds__(256) void conv_silu_k(
    const u16* __restrict__ xz,
    const float* __restrict__ wf, const float* __restrict__ bf,
    const float* __restrict__ wb, const float* __restrict__ bb,
    u16* __restrict__ xf, u16* __restrict__ xb)
{
  int idx = blockIdx.x * 256 + threadIdx.x;   // over LSEQ * (DINNER/8)
  int dir = blockIdx.y;
  int l = idx / (DINNER / 8), c8 = (idx % (DINNER / 8)) * 8;
  const float* w = (dir ? wb : wf) + c8 * KCONV;   // [8][4] contiguous
  const float* bias = (dir ? bb : bf) + c8;
  float acc[8];
#pragma unroll
  for (int j = 0; j < 8; j++) acc[j] = bias[j];
#pragma unroll
  for (int k = 0; k < KCONV; k++) {
    int ls = l - (KCONV - 1) + k;
    if (ls >= 0) {
      int lsrc = dir ? (LSEQ - 1 - ls) : ls;
      us8 v = *(const us8*)(xz + (size_t)lsrc * (2 * DINNER) + c8);
#pragma unroll
      for (int j = 0; j < 8; j++) acc[j] += w[j * KCONV + k] * bf2f(v[j]);
    }
  }
  us8 o;
#pragma unroll
  for (int j = 0; j < 8; j++) {
    float s = acc[j] / (1.f + __expf(-acc[j]));
    o[j] = f2bf(s);
  }
  *(us8*)((dir ? xb : xf) + (size_t)l * DINNER + c8) = o;
}

// ---------------- 3-phase L-split scan (round-15 form, fast-exp) -------------
__global__ __launch_bounds__(256) void scan_a_k(
    const u16* __restrict__ xcf, const u16* __restrict__ xcb,
    const u16* __restrict__ dltf, const u16* __restrict__ dltb,
    const float* __restrict__ dbcf, const float* __restrict__ dbcb,
    const float* __restrict__ Af, const float* __restrict__ Ab,
    float* __restrict__ qsP, float* __restrict__ qsQ)
{
  __shared__ float sP[SCH * SCW * DSTATE];
  __shared__ float sQ[SCH * SCW * DSTATE];
  const int dir = blockIdx.z;
  const int qid = blockIdx.y;   // 0..NQ-2 (last octave's summary never used)
  const u16*   xc    = dir ? xcb : xcf;
  const u16*   delta = dir ? dltb : dltf;
  const float* dbc   = dir ? dbcb : dbcf;
  const float* A_log = dir ? Ab : Af;

  const int tid = threadIdx.x;
  const int c = tid >> 5;
  const int dl = tid & 31;
  const int d = blockIdx.x * SCW + dl;

  float Aa[DSTATE];
#pragma unroll
  for (int s = 0; s < DSTATE; s++) Aa[s] = -__expf(A_log[(size_t)d * DSTATE + s]);
  const float Aa0 = Aa[0];
  bool fast = true;
#pragma unroll
  for (int s = 1; s < DSTATE; s++)
    fast = fast && (fabsf(Aa[s] - Aa0 * (float)(s + 1)) <= 1e-4f * fabsf(Aa[s]));

  float aP[DSTATE], q[DSTATE];
#pragma unroll
  for (int s = 0; s < DSTATE; s++) { aP[s] = 1.f; q[s] = 0.f; }
  const int l0 = qid * QL + c * QCH;
  if (fast) {
    for (int i = 0; i < QCH; i++) {
      int l = l0 + i;
      float dt = bf2f(delta[(size_t)l * DINNER + d]);
      float dx = dt * bf2f(xc[(size_t)l * DINNER + d]);
      const float* bm = dbc + (size_t)l * DBC + DRANK;
      float e0 = __expf(dt * Aa0);
      float a = 1.f;
#pragma unroll
      for (int s = 0; s < DSTATE; s++) {
        a *= e0;
        q[s] = a * q[s] + dx * bm[s];
        aP[s] *= a;
      }
    }
  } else {
    for (int i = 0; i < QCH; i++) {
      int l = l0 + i;
      float dt = bf2f(delta[(size_t)l * DINNER + d]);
      float dx = dt * bf2f(xc[(size_t)l * DINNER + d]);
      const float* bm = dbc + (size_t)l * DBC + DRANK;
#pragma unroll
      for (int s = 0; s < DSTATE; s++) {
        float a = __expf(dt * Aa[s]);
        q[s] = a * q[s] + dx * bm[s];
        aP[s] *= a;
      }
    }
  }
#pragma unroll
  for (int s = 0; s < DSTATE; s++) {
    sP[(c * SCW + dl) * DSTATE + s] = aP[s];
    sQ[(c * SCW + dl) * DSTATE + s] = q[s];
  }
  __syncthreads();

#pragma unroll
  for (int pp = 0; pp < 2; pp++) {
    const int p = tid + pp * 256;
    const int d2 = p >> 4, s2 = p & 15;
    float h = 0.f, P = 1.f;
    for (int cc = 0; cc < SCH; cc++) {
      int idx = (cc * SCW + d2) * DSTATE + s2;
      h = sP[idx] * h + sQ[idx];
      P *= sP[idx];
    }
    size_t o = (((size_t)dir * NQ + qid) * DINNER + blockIdx.x * SCW + d2) * DSTATE + s2;
    qsP[o] = P;
    qsQ[o] = h;
  }
}

__global__ __launch_bounds__(256) void scan_c_k(
    const u16* __restrict__ xcf, const u16* __restrict__ xcb,
    const u16* __restrict__ dltf, const u16* __restrict__ dltb,
    const float* __restrict__ dbcf, const float* __restrict__ dbcb,
    const float* __restrict__ Af, const float* __restrict__ Ab,
    const float* __restrict__ Df, const float* __restrict__ Db,
    const float* __restrict__ qsP, const float* __restrict__ qsQ,
    u16* __restrict__ ycat)
{
  __shared__ float sP[SCH * SCW * DSTATE];
  __shared__ float sQ[SCH * SCW * DSTATE];
  const int dir = blockIdx.z;
  const int qid = blockIdx.y;
  const u16*   xc    = dir ? xcb : xcf;
  const u16*   delta = dir ? dltb : dltf;
  const float* dbc   = dir ? dbcb : dbcf;
  const float* A_log = dir ? Ab : Af;
  const float* Dvec  = dir ? Db : Df;
  const int col_off  = dir ? DINNER : 0;

  const int tid = threadIdx.x;
  const int c = tid >> 5;
  const int dl = tid & 31;
  const int d = blockIdx.x * SCW + dl;

  float Aa[DSTATE];
#pragma unroll
  for (int s = 0; s < DSTATE; s++) Aa[s] = -__expf(A_log[(size_t)d * DSTATE + s]);
  const float Aa0 = Aa[0];
  bool fast = true;
#pragma unroll
  for (int s = 1; s < DSTATE; s++)
    fast = fast && (fabsf(Aa[s] - Aa0 * (float)(s + 1)) <= 1e-4f * fabsf(Aa[s]));

  float aP[DSTATE], q[DSTATE];
#pragma unroll
  for (int s = 0; s < DSTATE; s++) { aP[s] = 1.f; q[s] = 0.f; }
  const int l0 = qid * QL + c * QCH;
  if (fast) {
    for (int i = 0; i < QCH; i++) {
      int l = l0 + i;
      float dt = bf2f(delta[(size_t)l * DINNER + d]);
      float dx = dt * bf2f(xc[(size_t)l * DINNER + d]);
      const float* bm = dbc + (size_t)l * DBC + DRANK;
      float e0 = __expf(dt * Aa0);
      float a = 1.f;
#pragma unroll
      for (int s = 0; s < DSTATE; s++) {
        a *= e0;
        q[s] = a * q[s] + dx * bm[s];
        aP[s] *= a;
      }
    }
  } else {
    for (int i = 0; i < QCH; i++) {
      int l = l0 + i;
      float dt = bf2f(delta[(size_t)l * DINNER + d]);
      float dx = dt * bf2f(xc[(size_t)l * DINNER + d]);
      const float* bm = dbc + (size_t)l * DBC + DRANK;
#pragma unroll
      for (int s = 0; s < DSTATE; s++) {
        float a = __expf(dt * Aa[s]);
        q[s] = a * q[s] + dx * bm[s];
        aP[s] *= a;
      }
    }
  }
#pragma unroll
  for (int s = 0; s < DSTATE; s++) {
    sP[(c * SCW + dl) * DSTATE + s] = aP[s];
    sQ[(c * SCW + dl) * DSTATE + s] = q[s];
  }
  __syncthreads();

#pragma unroll
  for (int pp = 0; pp < 2; pp++) {
    const int p = tid + pp * 256;
    const int d2 = p >> 4, s2 = p & 15;
    float h = 0.f;
    for (int qq = 0; qq < qid; qq++) {
      size_t o = (((size_t)dir * NQ + qq) * DINNER + blockIdx.x * SCW + d2) * DSTATE + s2;
      h = qsP[o] * h + qsQ[o];
    }
    for (int cc = 0; cc < SCH; cc++) {
      int idx = (cc * SCW + d2) * DSTATE + s2;
      float a = sP[idx], qv = sQ[idx];
      sP[idx] = h;
      h = a * h + qv;
    }
  }
  __syncthreads();

  float hs[DSTATE];
#pragma unroll
  for (int s = 0; s < DSTATE; s++) hs[s] = sP[(c * SCW + dl) * DSTATE + s];
  const float Dd = Dvec[d];
  if (fast) {
    for (int i = 0; i < QCH; i++) {
      int l = l0 + i;
      float dt = bf2f(delta[(size_t)l * DINNER + d]);
      float xv = bf2f(xc[(size_t)l * DINNER + d]);
      float dx = dt * xv;
      const float* bm = dbc + (size_t)l * DBC + DRANK;
      const float* cm = bm + DSTATE;
      float e0 = __expf(dt * Aa0);
      float a = 1.f;
      float y = 0.f;
#pragma unroll
      for (int s = 0; s < DSTATE; s++) {
        a *= e0;
        hs[s] = a * hs[s] + dx * bm[s];
        y += hs[s] * cm[s];
      }
      ycat[(size_t)l * (2 * DINNER) + col_off + d] = f2bf(y + Dd * xv);
    }
  } else {
    for (int i = 0; i < QCH; i++) {
      int l = l0 + i;
      float dt = bf2f(delta[(size_t)l * DINNER + d]);
      float xv = bf2f(xc[(size_t)l * DINNER + d]);
      float dx = dt * xv;
      const float* bm = dbc + (size_t)l * DBC + DRANK;
      const float* cm = bm + DSTATE;
      float y = 0.f;
#pragma unroll
      for (int s = 0; s < DSTATE; s++) {
        float a = __expf(dt * Aa[s]);
        hs[s] = a * hs[s] + dx * bm[s];
        y += hs[s] * cm[s];
      }
      ycat[(size_t)l * (2 * DINNER) + col_off + d] = f2bf(y + Dd * xv);
    }
  }
}

// ---------------- row softmax (fp32 in, bf16 out) ----------------
__global__ __launch_bounds__(256) void softmax_k(const float* __restrict__ S,
                                                 u16* __restrict__ P) {
  int row = blockIdx.x, tid = threadIdx.x;
  __shared__ float buf[LSEQ];
  __shared__ float red[256];
  const float* r = S + (size_t)row * LSEQ;
  float m = -1e30f;
  for (int j = tid; j < LSEQ; j += 256) { float v = r[j]; buf[j] = v; m = fmaxf(m, v); }
  red[tid] = m; __syncthreads();
  for (int s = 128; s > 0; s >>= 1) { if (tid < s) red[tid] = fmaxf(red[tid], red[tid + s]); __syncthreads(); }
  m = red[0];
  __syncthreads();
  float sum = 0.f;
  for (int j = tid; j < LSEQ; j += 256) { float e = __expf(buf[j] - m); buf[j] = e; sum += e; }
  red[tid] = sum; __syncthreads();
  for (int s = 128; s > 0; s >>= 1) { if (tid < s) red[tid] += red[tid + s]; __syncthreads(); }
  float inv = 1.f / red[0];
  u16* pr = P + (size_t)row * LSEQ;
  for (int j = tid; j < LSEQ; j += 256) pr[j] = f2bf(buf[j] * inv);
}

extern "C" void kernel_launch(void* const* d_in, const int* in_sizes, int n_in,
                              void* d_out, int out_size, void* d_ws, size_t ws_size,
                              hipStream_t stream) {
  const float* in_x      = (const float*)d_in[0];
  const float* norm_w    = (const float*)d_in[1];
  const float* in_proj_w = (const float*)d_in[2];
  const float* conv_f_w  = (const float*)d_in[3];
  const float* conv_f_b  = (const float*)d_in[4];
  const float* conv_b_w  = (const float*)d_in[5];
  const float* conv_b_b  = (const float*)d_in[6];
  const float* xproj_f_w = (const float*)d_in[7];
  const float* xproj_b_w = (const float*)d_in[8];
  const float* dt_f_w    = (const float*)d_in[9];
  const float* dt_f_b    = (const float*)d_in[10];
  const float* dt_b_w    = (const float*)d_in[11];
  const float* dt_b_b    = (const float*)d_in[12];
  const float* A_log_f   = (const float*)d_in[13];
  const float* D_f       = (const float*)d_in[14];
  const float* A_log_b   = (const float*)d_in[15];
  const float* D_b       = (const float*)d_in[16];
  const float* out_w     = (const float*)d_in[17];
  const float* token_wA  = (const float*)d_in[18];
  const float* token_wV  = (const float*)d_in[19];
  const float* pro_w     = (const float*)d_in[20];
  const float* pro_b     = (const float*)d_in[21];

  // ---- workspace carve (fp32 units) ----
  float* ws = (float*)d_ws;
  float* xbuf = ws; ws += LSEQ * DMODEL;
  u16* xz_bf  = (u16*)ws; ws += LSEQ * DINNER;
  u16* xf_bf  = (u16*)ws; ws += (LSEQ * DINNER) / 2;
  u16* xb_bf  = (u16*)ws; ws += (LSEQ * DINNER) / 2;
  float* dbcf = ws; ws += LSEQ * DBC;
  float* dbcb = ws; ws += LSEQ * DBC;
  float* delf_r = ws; ws += LSEQ * DINNER;
  float* delb_r = ws; ws += LSEQ * DINNER;
  float* scr  = ws; ws += LSEQ * DINNER;
  u16* xn_bf   = (u16*)ws; ws += (LSEQ * DMODEL) / 2;
  u16* ycat_bf = (u16*)ws; ws += LSEQ * DINNER;
  u16* ypro_bf = (u16*)ws; ws += (LSEQ * DINNER) / 2;
  u16* Wb      = (u16*)ws;

  u16* in_w_bf0 = Wb;
  u16* pw_bf0   = in_w_bf0 + 3072 * 768;
  u16* wA_bf0   = pw_bf0 + 1536 * 3072;
  u16* wVT_bf0  = wA_bf0 + 1024 * 1536;
  u16* ow_bf0   = wVT_bf0 + 1536 * 1536;

  float* dbc_part = delf_r;
  u16*   delf_bf  = (u16*)delf_r;
  u16*   delb_bf  = (u16*)delb_r;
  float* Smat     = delf_r;
  u16*   Smat_bf  = (u16*)delb_r;
  u16*   vvT_bf   = xb_bf;        // xb dead after scan_c
  u16*   g_bf     = ypro_bf;
  const int QS = 2 * NQ * DINNER * DSTATE;
  float* qsP   = scr;
  float* qsQ   = scr + QS;

  dim3 blk(256);

  cvt4_k<<<dim3(CV3 / 256, NLAYER), blk, 0, stream>>>(
      in_proj_w, in_w_bf0, 2 * DINNER * DMODEL / 4,
      pro_w,     pw_bf0,   DINNER * 2 * DINNER / 4,
      token_wA,  wA_bf0,   LSEQ * DINNER / 4,
      out_w,     ow_bf0,   DMODEL * DINNER / 4);
  transcvt_k<<<dim3(1536 / 32, 1536 / 32, NLAYER), blk, 0, stream>>>(
      token_wV, wVT_bf0, 1536, 1536);

  for (int layer = 0; layer < NLAYER; layer++) {
    const float* nw  = norm_w    + (size_t)layer * DMODEL;
    const float* cfw = conv_f_w  + (size_t)layer * DINNER * KCONV;
    const float* cfb = conv_f_b  + (size_t)layer * DINNER;
    const float* cbw = conv_b_w  + (size_t)layer * DINNER * KCONV;
    const float* cbb = conv_b_b  + (size_t)layer * DINNER;
    const float* xfw = xproj_f_w + (size_t)layer * DBC * DINNER;
    const float* xbw = xproj_b_w + (size_t)layer * DBC * DINNER;
    const float* dfw = dt_f_w    + (size_t)layer * DINNER * DRANK;
    const float* dfb = dt_f_b    + (size_t)layer * DINNER;
    const float* dbw = dt_b_w    + (size_t)layer * DINNER * DRANK;
    const float* dbb = dt_b_b    + (size_t)layer * DINNER;
    const float* Af  = A_log_f   + (size_t)layer * DINNER * DSTATE;
    const float* Df  = D_f       + (size_t)layer * DINNER;
    const float* Ab  = A_log_b   + (size_t)layer * DINNER * DSTATE;
    const float* Db  = D_b       + (size_t)layer * DINNER;
    const float* pb  = pro_b     + (size_t)layer * DINNER;

    u16* in_w_bf = in_w_bf0 + (size_t)layer * WBL;
    u16* pw_bf   = pw_bf0   + (size_t)layer * WBL;
    u16* wA_bf   = wA_bf0   + (size_t)layer * WBL;
    u16* wVT_bf  = wVT_bf0  + (size_t)layer * WBL;
    u16* ow_bf   = ow_bf0   + (size_t)layer * WBL;

    const float* xsrc = (layer == 0) ? in_x : xbuf;

    rmsnorm_k<<<LSEQ, blk, 0, stream>>>(xsrc, nw, xn_bf);

    mgemmW_k<8><<<dim3(3072 / 128, LSEQ / 64), blk, 0, stream>>>(
        xn_bf, DMODEL, in_w_bf, DMODEL, xz_bf, 2 * DINNER, DMODEL, nullptr, nullptr, 0);

    conv_silu_k<<<dim3((LSEQ * DINNER / 8) / 256, 2), blk, 0, stream>>>(
        xz_bf, cfw, cfb, cbw, cbb, xf_bf, xb_bf);

    thin_gemm_k<<<dim3(LSEQ / TG_R, TG_KS, 2), blk, 0, stream>>>(
        xf_bf, xb_bf, xfw, xbw, dbc_part);
    reduce_dbc_k<<<dim3((LSEQ * DBC) / 256, 2), blk, 0, stream>>>(
        dbc_part, dbcf, dbcb);

    delta_gemm_k<<<dim3(DINNER / BN, LSEQ / BM, 2), blk, 0, stream>>>(
        dbcf, dbcb, dfw, dbw, dfb, dbb, delf_bf, delb_bf);

    scan_a_k<<<dim3(DINNER / SCW, NQ - 1, 2), blk, 0, stream>>>(
        xf_bf, xb_bf, delf_bf, delb_bf, dbcf, dbcb, Af, Ab, qsP, qsQ);
    scan_c_k<<<dim3(DINNER / SCW, NQ, 2), blk, 0, stream>>>(
        xf_bf, xb_bf, delf_bf, delb_bf, dbcf, dbcb, Af, Ab, Df, Db, qsP, qsQ, ycat_bf);

    mgemmW_k<9><<<dim3(DINNER / 128, LSEQ / 64), blk, 0, stream>>>(
        ycat_bf, 2 * DINNER, pw_bf, 2 * DINNER, ypro_bf, DINNER, 2 * DINNER,
        pb, nullptr, 0);

    svgemm_k<<<640, blk, 0, stream>>>(wA_bf, ypro_bf, wVT_bf, Smat, vvT_bf);
    softmax_k<<<LSEQ, blk, 0, stream>>>(Smat, Smat_bf);

    mgemmW_k<56><<<dim3(DINNER / 128, LSEQ / 64), blk, 0, stream>>>(
        Smat_bf, LSEQ, vvT_bf, LSEQ, g_bf, DINNER, LSEQ,
        nullptr, (const float*)(xz_bf + DINNER), 2 * DINNER);

    float* target = (layer == NLAYER - 1) ? (float*)d_out : xbuf;
    mgemm_k<4><<<dim3(DMODEL / 64, LSEQ / 64), blk, 0, stream>>>(
        g_bf, DINNER, ow_bf, DINNER, target, DMODEL, DINNER,
        nullptr, xsrc, DMODEL);
  }
}

// Round 18
// 398.475 us; speedup vs baseline: 1.0435x; 1.0435x over previous
//
#include <hip/hip_runtime.h>
#include <hip/hip_bf16.h>
#include <math.h>
#include <stdint.h>

#define LSEQ 1024
#define DMODEL 768
#define DINNER 1536
#define DSTATE 16
#define DRANK 48
#define KCONV 4
#define NLAYER 2
#define DBC 80  // DRANK + 2*DSTATE
#define NQ 8            // L-split for the 3-phase scan
#define QL (LSEQ / NQ)  // 128
#define SCH 8           // chunks per scan block
#define SCW 32          // channels per scan block (32*2B = full 64B line)
#define QCH (QL / SCH)  // 16 steps per chunk

typedef unsigned short u16;
typedef __attribute__((ext_vector_type(8))) __bf16 bf16x8;
typedef __attribute__((ext_vector_type(4))) float f32x4;
typedef __attribute__((ext_vector_type(4))) unsigned short us4;  // 4 u16 = 8 B

__device__ __forceinline__ u16 f2bf(float f) {
  union { float f; unsigned u; } v; v.f = f;
  unsigned r = v.u + 0x7fffu + ((v.u >> 16) & 1u);  // RNE
  return (u16)(r >> 16);
}
__device__ __forceinline__ float bf2f(u16 u) {
  union { unsigned u; float f; } v; v.u = ((unsigned)u) << 16;
  return v.f;
}

// CK-style addrspace casts for global_load_lds (direct HBM->LDS DMA, 16B/lane)
__device__ __forceinline__ void gload16(const void* g, void* l) {
  auto gp = reinterpret_cast<const __attribute__((address_space(1))) uint32_t*>(
      reinterpret_cast<uintptr_t>(g));
  auto lp = reinterpret_cast<__attribute__((address_space(3))) uint32_t*>(
      reinterpret_cast<uintptr_t>(l));
  __builtin_amdgcn_global_load_lds(gp, lp, 16, 0, 0);
}

// ------------- fused fp32 -> bf16 convert of 4 weight mats, BOTH layers ------
#define CV0 589824              // 3072*768/4
#define CV1 (CV0 + 1179648)     // +1536*3072/4
#define CV2 (CV1 + 393216)      // +1024*1536/4
#define CV3 (CV2 + 294912)      // +768*1536/4 = 2457600 total float4s
#define WBL 12189696            // per-layer bf16 weight region (u16 elems)
__global__ __launch_bounds__(256) void cvt4_k(
    const float* __restrict__ i0, u16* __restrict__ o0, int s0o,
    const float* __restrict__ i1, u16* __restrict__ o1, int s1o,
    const float* __restrict__ i2, u16* __restrict__ o2, int s2o,
    const float* __restrict__ i3, u16* __restrict__ o3, int s3o) {
  int i = blockIdx.x * 256 + threadIdx.x;
  int lay = blockIdx.y;
  const float* in; u16* out; int off;
  if (i < CV0)      { in = i0 + (size_t)lay * s0o * 4; out = o0 + (size_t)lay * WBL; off = i; }
  else if (i < CV1) { in = i1 + (size_t)lay * s1o * 4; out = o1 + (size_t)lay * WBL; off = i - CV0; }
  else if (i < CV2) { in = i2 + (size_t)lay * s2o * 4; out = o2 + (size_t)lay * WBL; off = i - CV1; }
  else              { in = i3 + (size_t)lay * s3o * 4; out = o3 + (size_t)lay * WBL; off = i - CV2; }
  float4 v = ((const float4*)in)[off];
  us4 o; o[0] = f2bf(v.x); o[1] = f2bf(v.y); o[2] = f2bf(v.z); o[3] = f2bf(v.w);
  ((us4*)out)[off] = o;
}

// ---------------- fp32 -> bf16 transpose-convert (both layers via z) ---------
__global__ __launch_bounds__(256) void transcvt_k(const float* __restrict__ in0,
                                                  u16* __restrict__ out0,
                                                  int R, int C) {
  __shared__ float t[32][33];
  const float* in = in0 + (size_t)blockIdx.z * R * C;
  u16* out = out0 + (size_t)blockIdx.z * WBL;
  int c0 = blockIdx.x * 32, r0 = blockIdx.y * 32;
  int tx = threadIdx.x & 31, ty = threadIdx.x >> 5;
  for (int i = ty; i < 32; i += 8) t[i][tx] = in[(size_t)(r0 + i) * C + c0 + tx];
  __syncthreads();
  for (int i = ty; i < 32; i += 8)
    out[(size_t)(c0 + i) * R + r0 + tx] = f2bf(t[tx][i]);
}

// ---------------- rmsnorm (bf16 out) ----------------
__global__ __launch_bounds__(256) void rmsnorm_k(const float* __restrict__ x,
                                                 const float* __restrict__ w,
                                                 u16* __restrict__ xn) {
  int row = blockIdx.x;
  int tid = threadIdx.x;
  const float* xr = x + (size_t)row * DMODEL;
  float ss = 0.f;
  for (int j = tid; j < DMODEL; j += 256) { float v = xr[j]; ss += v * v; }
  __shared__ float red[256];
  red[tid] = ss; __syncthreads();
  for (int s = 128; s > 0; s >>= 1) { if (tid < s) red[tid] += red[tid + s]; __syncthreads(); }
  float scale = rsqrtf(red[0] / (float)DMODEL + 1e-5f);
  u16* outr = xn + (size_t)row * DMODEL;
  for (int j = tid; j < DMODEL; j += 256) outr[j] = f2bf(xr[j] * scale * w[j]);
}

// ---------------- MFMA bf16 GEMM: 64x64 tile (kept for out GEMM) -------------
// EPI bit0: +bias; bit2: +resid fp32; bit3: bf16 out; bit4: *silu(resid);
// bit5: resid is bf16.
template<int EPI>
__global__ __launch_bounds__(256) void mgemm_k(
    const u16* __restrict__ A, int lda,
    const u16* __restrict__ B, int ldb,
    void* __restrict__ Cv, int ldc, int K,
    const float* __restrict__ bias,
    const float* __restrict__ resid, int ldr)
{
  __shared__ u16 As[2][64 * 64];
  __shared__ u16 Bs[2][64 * 64];
  const int tid = threadIdx.x;
  const int lane = tid & 63;
  const int w = tid >> 6;

  const int nbx = gridDim.x;
  int bid = blockIdx.y * nbx + blockIdx.x;
  const int nwg = nbx * gridDim.y;
  bid = (bid & 7) * (nwg >> 3) + (bid >> 3);
  const int bm = (bid / nbx) * 64;
  const int bn = (bid % nbx) * 64;

  const int srow = lane >> 3;
  const int scs = (lane & 7) ^ srow;
  const int gA = 2 * w;
  const u16* Asrc0 = A + (size_t)(bm + gA * 8 + srow) * lda + scs * 8;
  const u16* Asrc1 = Asrc0 + (size_t)8 * lda;
  const u16* Bsrc0 = B + (size_t)(bn + gA * 8 + srow) * ldb + scs * 8;
  const u16* Bsrc1 = Bsrc0 + (size_t)8 * ldb;
  const int d0 = gA * 512;
  const int d1 = d0 + 512;

  const int fr = lane & 15;
  const int fs = lane >> 4;
  const int wm = (w >> 1) * 32;
  const int wn = (w & 1) * 32;
  int aoff[2][2], boff[2][2];
#pragma unroll
  for (int i = 0; i < 2; i++)
#pragma unroll
    for (int h = 0; h < 2; h++) {
      const int g = h * 4 + fs;
      aoff[i][h] = (wm + i * 16 + fr) * 64 + (g ^ (fr & 7)) * 8;
      boff[i][h] = (wn + i * 16 + fr) * 64 + (g ^ (fr & 7)) * 8;
    }

  f32x4 acc[2][2];
#pragma unroll
  for (int i = 0; i < 2; i++)
#pragma unroll
    for (int j = 0; j < 2; j++) acc[i][j] = (f32x4){0.f, 0.f, 0.f, 0.f};

#define STAGE(buf, k0) do { \
    gload16(Asrc0 + (k0), &As[buf][d0]); \
    gload16(Asrc1 + (k0), &As[buf][d1]); \
    gload16(Bsrc0 + (k0), &Bs[buf][d0]); \
    gload16(Bsrc1 + (k0), &Bs[buf][d1]); \
  } while (0)

  const int nk = K >> 6;
  STAGE(0, 0);

  for (int t = 0; t < nk; t++) {
    const int buf = t & 1;
    __syncthreads();
    if (t + 1 < nk) STAGE(buf ^ 1, (t + 1) << 6);
    const u16* As_ = As[buf];
    const u16* Bs_ = Bs[buf];
#pragma unroll
    for (int h = 0; h < 2; h++) {
      bf16x8 a0 = *reinterpret_cast<const bf16x8*>(As_ + aoff[0][h]);
      bf16x8 a1 = *reinterpret_cast<const bf16x8*>(As_ + aoff[1][h]);
      bf16x8 b0 = *reinterpret_cast<const bf16x8*>(Bs_ + boff[0][h]);
      bf16x8 b1 = *reinterpret_cast<const bf16x8*>(Bs_ + boff[1][h]);
      acc[0][0] = __builtin_amdgcn_mfma_f32_16x16x32_bf16(a0, b0, acc[0][0], 0, 0, 0);
      acc[0][1] = __builtin_amdgcn_mfma_f32_16x16x32_bf16(a0, b1, acc[0][1], 0, 0, 0);
      acc[1][0] = __builtin_amdgcn_mfma_f32_16x16x32_bf16(a1, b0, acc[1][0], 0, 0, 0);
      acc[1][1] = __builtin_amdgcn_mfma_f32_16x16x32_bf16(a1, b1, acc[1][1], 0, 0, 0);
    }
  }
#undef STAGE

#pragma unroll
  for (int i = 0; i < 2; i++) {
#pragma unroll
    for (int j = 0; j < 2; j++) {
      const int col = bn + wn + j * 16 + fr;
      const int row0 = bm + wm + i * 16 + fs * 4;
      float bv = (EPI & 1) ? bias[col] : 0.f;
#pragma unroll
      for (int r = 0; r < 4; r++) {
        float v = acc[i][j][r] + bv;
        if (EPI & 4) v += resid[(size_t)(row0 + r) * ldr + col];
        if (EPI & 16) {
          float z = (EPI & 32)
              ? bf2f(((const u16*)resid)[(size_t)(row0 + r) * ldr + col])
              : resid[(size_t)(row0 + r) * ldr + col];
          v *= z / (1.f + __expf(-z));
        }
        if (EPI & 8) ((u16*)Cv)[(size_t)(row0 + r) * ldc + col] = f2bf(v);
        else         ((float*)Cv)[(size_t)(row0 + r) * ldc + col] = v;
      }
    }
  }
}

// ------- MFMA bf16 GEMM: 64x128 tile, 4 waves each 32x64 (2x4 frags) ---------
template<int EPI>
__global__ __launch_bounds__(256) void mgemmW_k(
    const u16* __restrict__ A, int lda,
    const u16* __restrict__ B, int ldb,
    void* __restrict__ Cv, int ldc, int K,
    const float* __restrict__ bias,
    const float* __restrict__ resid, int ldr)
{
  __shared__ u16 As[2][64 * 64];
  __shared__ u16 Bs[2][128 * 64];
  const int tid = threadIdx.x;
  const int lane = tid & 63;
  const int w = tid >> 6;

  const int nbx = gridDim.x;
  int bid = blockIdx.y * nbx + blockIdx.x;
  const int nwg = nbx * gridDim.y;
  bid = (bid & 7) * (nwg >> 3) + (bid >> 3);
  const int bm = (bid / nbx) * 64;
  const int bn = (bid % nbx) * 128;

  const int srow = lane >> 3;
  const int scs = (lane & 7) ^ srow;
  const u16* Asrc0 = A + (size_t)(bm + (2 * w) * 8 + srow) * lda + scs * 8;
  const u16* Asrc1 = Asrc0 + (size_t)8 * lda;
  const int da0 = (2 * w) * 512, da1 = da0 + 512;
  const u16* Bsrc0 = B + (size_t)(bn + (4 * w) * 8 + srow) * ldb + scs * 8;
  const u16* Bsrc1 = Bsrc0 + (size_t)8 * ldb;
  const u16* Bsrc2 = Bsrc1 + (size_t)8 * ldb;
  const u16* Bsrc3 = Bsrc2 + (size_t)8 * ldb;
  const int db0 = (4 * w) * 512;

  const int fr = lane & 15;
  const int fs = lane >> 4;
  const int wm = (w >> 1) * 32;
  const int wn = (w & 1) * 64;
  int aoff[2][2], boff[4][2];
#pragma unroll
  for (int h = 0; h < 2; h++) {
    const int g = h * 4 + fs;
    const int sw = (g ^ (fr & 7)) * 8;
#pragma unroll
    for (int i = 0; i < 2; i++) aoff[i][h] = (wm + i * 16 + fr) * 64 + sw;
#pragma unroll
    for (int j = 0; j < 4; j++) boff[j][h] = (wn + j * 16 + fr) * 64 + sw;
  }

  f32x4 acc[2][4];
#pragma unroll
  for (int i = 0; i < 2; i++)
#pragma unroll
    for (int j = 0; j < 4; j++) acc[i][j] = (f32x4){0.f, 0.f, 0.f, 0.f};

#define STAGEW(buf, k0) do { \
    gload16(Asrc0 + (k0), &As[buf][da0]); \
    gload16(Asrc1 + (k0), &As[buf][da1]); \
    gload16(Bsrc0 + (k0), &Bs[buf][db0]); \
    gload16(Bsrc1 + (k0), &Bs[buf][db0 + 512]); \
    gload16(Bsrc2 + (k0), &Bs[buf][db0 + 1024]); \
    gload16(Bsrc3 + (k0), &Bs[buf][db0 + 1536]); \
  } while (0)

  const int nk = K >> 6;
  STAGEW(0, 0);

  for (int t = 0; t < nk; t++) {
    const int buf = t & 1;
    __syncthreads();
    if (t + 1 < nk) STAGEW(buf ^ 1, (t + 1) << 6);
    const u16* As_ = As[buf];
    const u16* Bs_ = Bs[buf];
#pragma unroll
    for (int h = 0; h < 2; h++) {
      bf16x8 a0 = *reinterpret_cast<const bf16x8*>(As_ + aoff[0][h]);
      bf16x8 a1 = *reinterpret_cast<const bf16x8*>(As_ + aoff[1][h]);
#pragma unroll
      for (int j = 0; j < 4; j++) {
        bf16x8 b = *reinterpret_cast<const bf16x8*>(Bs_ + boff[j][h]);
        acc[0][j] = __builtin_amdgcn_mfma_f32_16x16x32_bf16(a0, b, acc[0][j], 0, 0, 0);
        acc[1][j] = __builtin_amdgcn_mfma_f32_16x16x32_bf16(a1, b, acc[1][j], 0, 0, 0);
      }
    }
  }
#undef STAGEW

#pragma unroll
  for (int i = 0; i < 2; i++) {
#pragma unroll
    for (int j = 0; j < 4; j++) {
      const int col = bn + wn + j * 16 + fr;
      const int row0 = bm + wm + i * 16 + fs * 4;
      float bv = (EPI & 1) ? bias[col] : 0.f;
#pragma unroll
      for (int r = 0; r < 4; r++) {
        float v = acc[i][j][r] + bv;
        if (EPI & 4) v += resid[(size_t)(row0 + r) * ldr + col];
        if (EPI & 16) {
          float z = (EPI & 32)
              ? bf2f(((const u16*)resid)[(size_t)(row0 + r) * ldr + col])
              : resid[(size_t)(row0 + r) * ldr + col];
          v *= z / (1.f + __expf(-z));
        }
        if (EPI & 8) ((u16*)Cv)[(size_t)(row0 + r) * ldc + col] = f2bf(v);
        else         ((float*)Cv)[(size_t)(row0 + r) * ldc + col] = v;
      }
    }
  }
}

// ---------------- fused S + vv GEMM; vv part writes vvT directly -------------
__global__ __launch_bounds__(256) void svgemm_k(
    const u16* __restrict__ wA, const u16* __restrict__ ypro,
    const u16* __restrict__ wVT,
    float* __restrict__ Smat, u16* __restrict__ vvT)
{
  __shared__ u16 As[2][64 * 64];
  __shared__ u16 Bs[2][64 * 64];
  __shared__ u16 tr[4][32][33];
  const int tid = threadIdx.x;
  const int lane = tid & 63;
  const int w = tid >> 6;

  int bid = blockIdx.x;
  bid = (bid & 7) * 80 + (bid >> 3);
  const bool is_s = bid < 256;
  const u16* A;
  const u16* B;
  int bm, bn;
  if (is_s) { A = wA;   B = ypro; bm = (bid >> 4) * 64;         bn = (bid & 15) * 64; }
  else      { A = ypro; B = wVT;  bm = ((bid - 256) / 24) * 64; bn = ((bid - 256) % 24) * 64; }

  const int srow = lane >> 3;
  const int scs = (lane & 7) ^ srow;
  const int gA = 2 * w;
  const u16* Asrc0 = A + (size_t)(bm + gA * 8 + srow) * DINNER + scs * 8;
  const u16* Asrc1 = Asrc0 + (size_t)8 * DINNER;
  const u16* Bsrc0 = B + (size_t)(bn + gA * 8 + srow) * DINNER + scs * 8;
  const u16* Bsrc1 = Bsrc0 + (size_t)8 * DINNER;
  const int d0 = gA * 512;
  const int d1 = d0 + 512;

  const int fr = lane & 15;
  const int fs = lane >> 4;
  const int wm = (w >> 1) * 32;
  const int wn = (w & 1) * 32;
  int aoff[2][2], boff[2][2];
#pragma unroll
  for (int i = 0; i < 2; i++)
#pragma unroll
    for (int h = 0; h < 2; h++) {
      const int g = h * 4 + fs;
      aoff[i][h] = (wm + i * 16 + fr) * 64 + (g ^ (fr & 7)) * 8;
      boff[i][h] = (wn + i * 16 + fr) * 64 + (g ^ (fr & 7)) * 8;
    }

  f32x4 acc[2][2];
#pragma unroll
  for (int i = 0; i < 2; i++)
#pragma unroll
    for (int j = 0; j < 2; j++) acc[i][j] = (f32x4){0.f, 0.f, 0.f, 0.f};

#define STAGE(buf, k0) do { \
    gload16(Asrc0 + (k0), &As[buf][d0]); \
    gload16(Asrc1 + (k0), &As[buf][d1]); \
    gload16(Bsrc0 + (k0), &Bs[buf][d0]); \
    gload16(Bsrc1 + (k0), &Bs[buf][d1]); \
  } while (0)

  STAGE(0, 0);
  for (int t = 0; t < DINNER / 64; t++) {
    const int buf = t & 1;
    __syncthreads();
    if (t + 1 < DINNER / 64) STAGE(buf ^ 1, (t + 1) << 6);
    const u16* As_ = As[buf];
    const u16* Bs_ = Bs[buf];
#pragma unroll
    for (int h = 0; h < 2; h++) {
      bf16x8 a0 = *reinterpret_cast<const bf16x8*>(As_ + aoff[0][h]);
      bf16x8 a1 = *reinterpret_cast<const bf16x8*>(As_ + aoff[1][h]);
      bf16x8 b0 = *reinterpret_cast<const bf16x8*>(Bs_ + boff[0][h]);
      bf16x8 b1 = *reinterpret_cast<const bf16x8*>(Bs_ + boff[1][h]);
      acc[0][0] = __builtin_amdgcn_mfma_f32_16x16x32_bf16(a0, b0, acc[0][0], 0, 0, 0);
      acc[0][1] = __builtin_amdgcn_mfma_f32_16x16x32_bf16(a0, b1, acc[0][1], 0, 0, 0);
      acc[1][0] = __builtin_amdgcn_mfma_f32_16x16x32_bf16(a1, b0, acc[1][0], 0, 0, 0);
      acc[1][1] = __builtin_amdgcn_mfma_f32_16x16x32_bf16(a1, b1, acc[1][1], 0, 0, 0);
    }
  }
#undef STAGE

  if (is_s) {
#pragma unroll
    for (int i = 0; i < 2; i++)
#pragma unroll
      for (int j = 0; j < 2; j++) {
        const int col = bn + wn + j * 16 + fr;
        const int row0 = bm + wm + i * 16 + fs * 4;
#pragma unroll
        for (int r = 0; r < 4; r++)
          Smat[(size_t)(row0 + r) * LSEQ + col] = acc[i][j][r];
      }
  } else {
#pragma unroll
    for (int i = 0; i < 2; i++)
#pragma unroll
      for (int j = 0; j < 2; j++) {
        const int lr0 = i * 16 + fs * 4;
        const int lc = j * 16 + fr;
#pragma unroll
        for (int r = 0; r < 4; r++) tr[w][lr0 + r][lc] = f2bf(acc[i][j][r]);
      }
    __syncthreads();
    const int lc = lane >> 1;
    const int half = lane & 1;
    const int gcol = bn + wn + lc;
    const int grow0 = bm + wm + half * 16;
    u16* dst = vvT + (size_t)gcol * LSEQ + grow0;
#pragma unroll
    for (int q = 0; q < 4; q++) {
      us4 v;
#pragma unroll
      for (int e = 0; e < 4; e++) v[e] = tr[w][half * 16 + q * 4 + e][lc];
      *(us4*)(dst + q * 4) = v;
    }
  }
}

// ---------------- thin dbc GEMM (bf16 A, f+b merged) -------------------------
#define TG_R 16
#define TG_KC 96
#define TG_KS 16

__global__ __launch_bounds__(256) void thin_gemm_k(
    const u16* __restrict__ Af_, const u16* __restrict__ Ab_,
    const float* __restrict__ Bf_, const float* __restrict__ Bb_,
    float* __restrict__ partial)
{
  __shared__ u16 As[TG_R][TG_KC];
  __shared__ float Bs[80][100];
  const u16* A = blockIdx.z ? Ab_ : Af_;
  const float* B = blockIdx.z ? Bb_ : Bf_;
  float* part = partial + (size_t)blockIdx.z * TG_KS * LSEQ * DBC;
  const int tid = threadIdx.x;
  const int m0 = blockIdx.x * TG_R;
  const int ks = blockIdx.y;
  const int k0 = ks * TG_KC;

  for (int i = tid; i < 384; i += 256) {
    int r = i / 24, q = i % 24;
    *(us4*)&As[r][q * 4] = *(const us4*)(A + (size_t)(m0 + r) * DINNER + k0 + q * 4);
  }
  for (int i = tid; i < 1920; i += 256) {
    int r = i / 24, q = i % 24;
    *(float4*)&Bs[r][q * 4] = *(const float4*)(B + (size_t)r * DINNER + k0 + q * 4);
  }
  __syncthreads();

  const int r = tid >> 4;
  const int c0 = (tid & 15) * 5;
  float acc[5] = {};
  for (int k = 0; k < TG_KC; k++) {
    float a = bf2f(As[r][k]);
#pragma unroll
    for (int j = 0; j < 5; j++) acc[j] += a * Bs[c0 + j][k];
  }
  float* out = part + ((size_t)ks * LSEQ + m0 + r) * DBC + c0;
#pragma unroll
  for (int j = 0; j < 5; j++) out[j] = acc[j];
}

__global__ __launch_bounds__(256) void reduce_dbc_k(const float* __restrict__ partial,
                                                    float* __restrict__ outf,
                                                    float* __restrict__ outb) {
  int i = blockIdx.x * 256 + threadIdx.x;
  const float* part = partial + (size_t)blockIdx.y * TG_KS * LSEQ * DBC;
  float s = 0.f;
#pragma unroll
  for (int ks = 0; ks < TG_KS; ks++) s += part[(size_t)ks * (LSEQ * DBC) + i];
  (blockIdx.y ? outb : outf)[i] = s;
}

// ---------------- delta = softplus(dlt @ dt_w^T + dt_b), f+b merged, bf16 out
#define BM 64
#define BN 64
#define BK 16

__global__ __launch_bounds__(256) void delta_gemm_k(
    const float* __restrict__ A0, const float* __restrict__ A1,
    const float* __restrict__ B0, const float* __restrict__ B1,
    const float* __restrict__ b0, const float* __restrict__ b1,
    u16* __restrict__ C0, u16* __restrict__ C1)
{
  __shared__ float Asf[BK][BM];
  __shared__ float Bsf[BK][BN + 4];
  const float* A = blockIdx.z ? A1 : A0;
  const float* B = blockIdx.z ? B1 : B0;
  const float* bias = blockIdx.z ? b1 : b0;
  u16* C = blockIdx.z ? C1 : C0;
  const int tid = threadIdx.x;
  const int bm = blockIdx.y * BM;
  const int bn = blockIdx.x * BN;
  const int ar = tid >> 2;
  const int ak = (tid & 3) << 2;
  const int ty = tid >> 4, tx = tid & 15;
  float acc[4][4] = {};

  for (int k0 = 0; k0 < DRANK; k0 += BK) {
    float4 av = *(const float4*)(A + (size_t)(bm + ar) * DBC + k0 + ak);
    float4 bv = *(const float4*)(B + (size_t)(bn + ar) * DRANK + k0 + ak);
    __syncthreads();
    Asf[ak + 0][ar] = av.x; Asf[ak + 1][ar] = av.y;
    Asf[ak + 2][ar] = av.z; Asf[ak + 3][ar] = av.w;
    Bsf[ak + 0][ar] = bv.x; Bsf[ak + 1][ar] = bv.y;
    Bsf[ak + 2][ar] = bv.z; Bsf[ak + 3][ar] = bv.w;
    __syncthreads();
#pragma unroll
    for (int kk = 0; kk < BK; kk++) {
      float4 a4 = *(const float4*)&Asf[kk][ty * 4];
      float4 b4 = *(const float4*)&Bsf[kk][tx * 4];
      float a[4] = {a4.x, a4.y, a4.z, a4.w};
      float b[4] = {b4.x, b4.y, b4.z, b4.w};
#pragma unroll
      for (int i = 0; i < 4; i++)
#pragma unroll
        for (int j = 0; j < 4; j++)
          acc[i][j] += a[i] * b[j];
    }
  }

#pragma unroll
  for (int i = 0; i < 4; i++) {
    int row = bm + ty * 4 + i;
#pragma unroll
    for (int j = 0; j < 4; j++) {
      int col = bn + tx * 4 + j;
      float v = acc[i][j] + bias[col];
      v = (v > 20.f) ? v : log1pf(__expf(v));
      C[(size_t)row * DINNER + col] = f2bf(v);
    }
  }
}

// ---------------- causal depthwise conv + silu (bf16 in/out, both dirs) ------
__global__ __launch_bounds__(256) void conv_silu_k(
    const u16* __restrict__ xz,
    const float* __restrict__ wf, const float* __restrict__ bf,
    const float* __restrict__ wb, const float* __restrict__ bb,
    u16* __restrict__ xf, u16* __restrict__ xb)
{
  int idx = blockIdx.x * 256 + threadIdx.x;
  int dir = blockIdx.y;
  if (idx >= LSEQ * DINNER) return;
  int l = idx / DINNER, c = idx % DINNER;
  const float* w = (dir ? wb : wf) + c * KCONV;
  float acc = (dir ? bb : bf)[c];
#pragma unroll
  for (int k = 0; k < KCONV; k++) {
    int ls = l - (KCONV - 1) + k;
    if (ls >= 0) {
      int lsrc = dir ? (LSEQ - 1 - ls) : ls;
      acc += w[k] * bf2f(xz[(size_t)lsrc * (2 * DINNER) + c]);
    }
  }
  float sv = acc / (1.f + __expf(-acc));
  (dir ? xb : xf)[idx] = f2bf(sv);
}

// ---------------- 3-phase L-split scan (fast-exp) ----------------------------
// FAST-EXP: A_log = log(1..16) in this model, so Aa[s] = Aa0*(s+1) and
// exp(dt*Aa[s]) = exp(dt*Aa0)^(s+1) — 1 exp + 15 muls instead of 16 exps.
// Verified per-thread with rel tol 1e-4; generic exp fallback otherwise.
__global__ __launch_bounds__(256) void scan_a_k(
    const u16* __restrict__ xcf, const u16* __restrict__ xcb,
    const u16* __restrict__ dltf, const u16* __restrict__ dltb,
    const float* __restrict__ dbcf, const float* __restrict__ dbcb,
    const float* __restrict__ Af, const float* __restrict__ Ab,
    float* __restrict__ qsP, float* __restrict__ qsQ)
{
  __shared__ float sP[SCH * SCW * DSTATE];
  __shared__ float sQ[SCH * SCW * DSTATE];
  const int dir = blockIdx.z;
  const int qid = blockIdx.y;   // 0..NQ-2 (last octave's summary never used)
  const u16*   xc    = dir ? xcb : xcf;
  const u16*   delta = dir ? dltb : dltf;
  const float* dbc   = dir ? dbcb : dbcf;
  const float* A_log = dir ? Ab : Af;

  const int tid = threadIdx.x;
  const int c = tid >> 5;
  const int dl = tid & 31;
  const int d = blockIdx.x * SCW + dl;

  float Aa[DSTATE];
#pragma unroll
  for (int s = 0; s < DSTATE; s++) Aa[s] = -__expf(A_log[(size_t)d * DSTATE + s]);
  const float Aa0 = Aa[0];
  bool fast = true;
#pragma unroll
  for (int s = 1; s < DSTATE; s++)
    fast = fast && (fabsf(Aa[s] - Aa0 * (float)(s + 1)) <= 1e-4f * fabsf(Aa[s]));

  float aP[DSTATE], q[DSTATE];
#pragma unroll
  for (int s = 0; s < DSTATE; s++) { aP[s] = 1.f; q[s] = 0.f; }
  const int l0 = qid * QL + c * QCH;
  if (fast) {
    for (int i = 0; i < QCH; i++) {
      int l = l0 + i;
      float dt = bf2f(delta[(size_t)l * DINNER + d]);
      float dx = dt * bf2f(xc[(size_t)l * DINNER + d]);
      const float* bm = dbc + (size_t)l * DBC + DRANK;
      float e0 = __expf(dt * Aa0);
      float a = 1.f;
#pragma unroll
      for (int s = 0; s < DSTATE; s++) {
        a *= e0;
        q[s] = a * q[s] + dx * bm[s];
        aP[s] *= a;
      }
    }
  } else {
    for (int i = 0; i < QCH; i++) {
      int l = l0 + i;
      float dt = bf2f(delta[(size_t)l * DINNER + d]);
      float dx = dt * bf2f(xc[(size_t)l * DINNER + d]);
      const float* bm = dbc + (size_t)l * DBC + DRANK;
#pragma unroll
      for (int s = 0; s < DSTATE; s++) {
        float a = __expf(dt * Aa[s]);
        q[s] = a * q[s] + dx * bm[s];
        aP[s] *= a;
      }
    }
  }
#pragma unroll
  for (int s = 0; s < DSTATE; s++) {
    sP[(c * SCW + dl) * DSTATE + s] = aP[s];
    sQ[(c * SCW + dl) * DSTATE + s] = q[s];
  }
  __syncthreads();

#pragma unroll
  for (int pp = 0; pp < 2; pp++) {
    const int p = tid + pp * 256;
    const int d2 = p >> 4, s2 = p & 15;
    float h = 0.f, P = 1.f;
    for (int cc = 0; cc < SCH; cc++) {
      int idx = (cc * SCW + d2) * DSTATE + s2;
      h = sP[idx] * h + sQ[idx];
      P *= sP[idx];
    }
    size_t o = (((size_t)dir * NQ + qid) * DINNER + blockIdx.x * SCW + d2) * DSTATE + s2;
    qsP[o] = P;
    qsQ[o] = h;
  }
}

__global__ __launch_bounds__(256) void scan_c_k(
    const u16* __restrict__ xcf, const u16* __restrict__ xcb,
    const u16* __restrict__ dltf, const u16* __restrict__ dltb,
    const float* __restrict__ dbcf, const float* __restrict__ dbcb,
    const float* __restrict__ Af, const float* __restrict__ Ab,
    const float* __restrict__ Df, const float* __restrict__ Db,
    const float* __restrict__ qsP, const float* __restrict__ qsQ,
    u16* __restrict__ ycat)
{
  __shared__ float sP[SCH * SCW * DSTATE];
  __shared__ float sQ[SCH * SCW * DSTATE];
  const int dir = blockIdx.z;
  const int qid = blockIdx.y;
  const u16*   xc    = dir ? xcb : xcf;
  const u16*   delta = dir ? dltb : dltf;
  const float* dbc   = dir ? dbcb : dbcf;
  const float* A_log = dir ? Ab : Af;
  const float* Dvec  = dir ? Db : Df;
  const int col_off  = dir ? DINNER : 0;

  const int tid = threadIdx.x;
  const int c = tid >> 5;
  const int dl = tid & 31;
  const int d = blockIdx.x * SCW + dl;

  float Aa[DSTATE];
#pragma unroll
  for (int s = 0; s < DSTATE; s++) Aa[s] = -__expf(A_log[(size_t)d * DSTATE + s]);
  const float Aa0 = Aa[0];
  bool fast = true;
#pragma unroll
  for (int s = 1; s < DSTATE; s++)
    fast = fast && (fabsf(Aa[s] - Aa0 * (float)(s + 1)) <= 1e-4f * fabsf(Aa[s]));

  float aP[DSTATE], q[DSTATE];
#pragma unroll
  for (int s = 0; s < DSTATE; s++) { aP[s] = 1.f; q[s] = 0.f; }
  const int l0 = qid * QL + c * QCH;
  if (fast) {
    for (int i = 0; i < QCH; i++) {
      int l = l0 + i;
      float dt = bf2f(delta[(size_t)l * DINNER + d]);
      float dx = dt * bf2f(xc[(size_t)l * DINNER + d]);
      const float* bm = dbc + (size_t)l * DBC + DRANK;
      float e0 = __expf(dt * Aa0);
      float a = 1.f;
#pragma unroll
      for (int s = 0; s < DSTATE; s++) {
        a *= e0;
        q[s] = a * q[s] + dx * bm[s];
        aP[s] *= a;
      }
    }
  } else {
    for (int i = 0; i < QCH; i++) {
      int l = l0 + i;
      float dt = bf2f(delta[(size_t)l * DINNER + d]);
      float dx = dt * bf2f(xc[(size_t)l * DINNER + d]);
      const float* bm = dbc + (size_t)l * DBC + DRANK;
#pragma unroll
      for (int s = 0; s < DSTATE; s++) {
        float a = __expf(dt * Aa[s]);
        q[s] = a * q[s] + dx * bm[s];
        aP[s] *= a;
      }
    }
  }
#pragma unroll
  for (int s = 0; s < DSTATE; s++) {
    sP[(c * SCW + dl) * DSTATE + s] = aP[s];
    sQ[(c * SCW + dl) * DSTATE + s] = q[s];
  }
  __syncthreads();

#pragma unroll
  for (int pp = 0; pp < 2; pp++) {
    const int p = tid + pp * 256;
    const int d2 = p >> 4, s2 = p & 15;
    float h = 0.f;
    for (int qq = 0; qq < qid; qq++) {
      size_t o = (((size_t)dir * NQ + qq) * DINNER + blockIdx.x * SCW + d2) * DSTATE + s2;
      h = qsP[o] * h + qsQ[o];
    }
    for (int cc = 0; cc < SCH; cc++) {
      int idx = (cc * SCW + d2) * DSTATE + s2;
      float a = sP[idx], qv = sQ[idx];
      sP[idx] = h;
      h = a * h + qv;
    }
  }
  __syncthreads();

  float hs[DSTATE];
#pragma unroll
  for (int s = 0; s < DSTATE; s++) hs[s] = sP[(c * SCW + dl) * DSTATE + s];
  const float Dd = Dvec[d];
  if (fast) {
    for (int i = 0; i < QCH; i++) {
      int l = l0 + i;
      float dt = bf2f(delta[(size_t)l * DINNER + d]);
      float xv = bf2f(xc[(size_t)l * DINNER + d]);
      float dx = dt * xv;
      const float* bm = dbc + (size_t)l * DBC + DRANK;
      const float* cm = bm + DSTATE;
      float e0 = __expf(dt * Aa0);
      float a = 1.f;
      float y = 0.f;
#pragma unroll
      for (int s = 0; s < DSTATE; s++) {
        a *= e0;
        hs[s] = a * hs[s] + dx * bm[s];
        y += hs[s] * cm[s];
      }
      ycat[(size_t)l * (2 * DINNER) + col_off + d] = f2bf(y + Dd * xv);
    }
  } else {
    for (int i = 0; i < QCH; i++) {
      int l = l0 + i;
      float dt = bf2f(delta[(size_t)l * DINNER + d]);
      float xv = bf2f(xc[(size_t)l * DINNER + d]);
      float dx = dt * xv;
      const float* bm = dbc + (size_t)l * DBC + DRANK;
      const float* cm = bm + DSTATE;
      float y = 0.f;
#pragma unroll
      for (int s = 0; s < DSTATE; s++) {
        float a = __expf(dt * Aa[s]);
        hs[s] = a * hs[s] + dx * bm[s];
        y += hs[s] * cm[s];
      }
      ycat[(size_t)l * (2 * DINNER) + col_off + d] = f2bf(y + Dd * xv);
    }
  }
}

// ---------------- row softmax (fp32 in, bf16 out) ----------------
__global__ __launch_bounds__(256) void softmax_k(const float* __restrict__ S,
                                                 u16* __restrict__ P) {
  int row = blockIdx.x, tid = threadIdx.x;
  __shared__ float buf[LSEQ];
  __shared__ float red[256];
  const float* r = S + (size_t)row * LSEQ;
  float m = -1e30f;
  for (int j = tid; j < LSEQ; j += 256) { float v = r[j]; buf[j] = v; m = fmaxf(m, v); }
  red[tid] = m; __syncthreads();
  for (int s = 128; s > 0; s >>= 1) { if (tid < s) red[tid] = fmaxf(red[tid], red[tid + s]); __syncthreads(); }
  m = red[0];
  __syncthreads();
  float sum = 0.f;
  for (int j = tid; j < LSEQ; j += 256) { float e = __expf(buf[j] - m); buf[j] = e; sum += e; }
  red[tid] = sum; __syncthreads();
  for (int s = 128; s > 0; s >>= 1) { if (tid < s) red[tid] += red[tid + s]; __syncthreads(); }
  float inv = 1.f / red[0];
  u16* pr = P + (size_t)row * LSEQ;
  for (int j = tid; j < LSEQ; j += 256) pr[j] = f2bf(buf[j] * inv);
}

extern "C" void kernel_launch(void* const* d_in, const int* in_sizes, int n_in,
                              void* d_out, int out_size, void* d_ws, size_t ws_size,
                              hipStream_t stream) {
  const float* in_x      = (const float*)d_in[0];
  const float* norm_w    = (const float*)d_in[1];
  const float* in_proj_w = (const float*)d_in[2];
  const float* conv_f_w  = (const float*)d_in[3];
  const float* conv_f_b  = (const float*)d_in[4];
  const float* conv_b_w  = (const float*)d_in[5];
  const float* conv_b_b  = (const float*)d_in[6];
  const float* xproj_f_w = (const float*)d_in[7];
  const float* xproj_b_w = (const float*)d_in[8];
  const float* dt_f_w    = (const float*)d_in[9];
  const float* dt_f_b    = (const float*)d_in[10];
  const float* dt_b_w    = (const float*)d_in[11];
  const float* dt_b_b    = (const float*)d_in[12];
  const float* A_log_f   = (const float*)d_in[13];
  const float* D_f       = (const float*)d_in[14];
  const float* A_log_b   = (const float*)d_in[15];
  const float* D_b       = (const float*)d_in[16];
  const float* out_w     = (const float*)d_in[17];
  const float* token_wA  = (const float*)d_in[18];
  const float* token_wV  = (const float*)d_in[19];
  const float* pro_w     = (const float*)d_in[20];
  const float* pro_b     = (const float*)d_in[21];

  // ---- workspace carve (fp32 units) ----
  float* ws = (float*)d_ws;
  float* xbuf = ws; ws += LSEQ * DMODEL;
  u16* xz_bf  = (u16*)ws; ws += LSEQ * DINNER;
  u16* xf_bf  = (u16*)ws; ws += (LSEQ * DINNER) / 2;
  u16* xb_bf  = (u16*)ws; ws += (LSEQ * DINNER) / 2;
  float* dbcf = ws; ws += LSEQ * DBC;
  float* dbcb = ws; ws += LSEQ * DBC;
  float* delf_r = ws; ws += LSEQ * DINNER;
  float* delb_r = ws; ws += LSEQ * DINNER;
  float* scr  = ws; ws += LSEQ * DINNER;
  u16* xn_bf   = (u16*)ws; ws += (LSEQ * DMODEL) / 2;
  u16* ycat_bf = (u16*)ws; ws += LSEQ * DINNER;
  u16* ypro_bf = (u16*)ws; ws += (LSEQ * DINNER) / 2;
  u16* Wb      = (u16*)ws;

  u16* in_w_bf0 = Wb;
  u16* pw_bf0   = in_w_bf0 + 3072 * 768;
  u16* wA_bf0   = pw_bf0 + 1536 * 3072;
  u16* wVT_bf0  = wA_bf0 + 1024 * 1536;
  u16* ow_bf0   = wVT_bf0 + 1536 * 1536;

  float* dbc_part = delf_r;
  u16*   delf_bf  = (u16*)delf_r;
  u16*   delb_bf  = (u16*)delb_r;
  float* Smat     = delf_r;
  u16*   Smat_bf  = (u16*)delb_r;
  u16*   vvT_bf   = xb_bf;        // xb dead after scan_c
  u16*   g_bf     = ypro_bf;
  const int QS = 2 * NQ * DINNER * DSTATE;
  float* qsP   = scr;
  float* qsQ   = scr + QS;

  dim3 blk(256);

  cvt4_k<<<dim3(CV3 / 256, NLAYER), blk, 0, stream>>>(
      in_proj_w, in_w_bf0, 2 * DINNER * DMODEL / 4,
      pro_w,     pw_bf0,   DINNER * 2 * DINNER / 4,
      token_wA,  wA_bf0,   LSEQ * DINNER / 4,
      out_w,     ow_bf0,   DMODEL * DINNER / 4);
  transcvt_k<<<dim3(1536 / 32, 1536 / 32, NLAYER), blk, 0, stream>>>(
      token_wV, wVT_bf0, 1536, 1536);

  for (int layer = 0; layer < NLAYER; layer++) {
    const float* nw  = norm_w    + (size_t)layer * DMODEL;
    const float* cfw = conv_f_w  + (size_t)layer * DINNER * KCONV;
    const float* cfb = conv_f_b  + (size_t)layer * DINNER;
    const float* cbw = conv_b_w  + (size_t)layer * DINNER * KCONV;
    const float* cbb = conv_b_b  + (size_t)layer * DINNER;
    const float* xfw = xproj_f_w + (size_t)layer * DBC * DINNER;
    const float* xbw = xproj_b_w + (size_t)layer * DBC * DINNER;
    const float* dfw = dt_f_w    + (size_t)layer * DINNER * DRANK;
    const float* dfb = dt_f_b    + (size_t)layer * DINNER;
    const float* dbw = dt_b_w    + (size_t)layer * DINNER * DRANK;
    const float* dbb = dt_b_b    + (size_t)layer * DINNER;
    const float* Af  = A_log_f   + (size_t)layer * DINNER * DSTATE;
    const float* Df  = D_f       + (size_t)layer * DINNER;
    const float* Ab  = A_log_b   + (size_t)layer * DINNER * DSTATE;
    const float* Db  = D_b       + (size_t)layer * DINNER;
    const float* pb  = pro_b     + (size_t)layer * DINNER;

    u16* in_w_bf = in_w_bf0 + (size_t)layer * WBL;
    u16* pw_bf   = pw_bf0   + (size_t)layer * WBL;
    u16* wA_bf   = wA_bf0   + (size_t)layer * WBL;
    u16* wVT_bf  = wVT_bf0  + (size_t)layer * WBL;
    u16* ow_bf   = ow_bf0   + (size_t)layer * WBL;

    const float* xsrc = (layer == 0) ? in_x : xbuf;

    rmsnorm_k<<<LSEQ, blk, 0, stream>>>(xsrc, nw, xn_bf);

    mgemmW_k<8><<<dim3(3072 / 128, LSEQ / 64), blk, 0, stream>>>(
        xn_bf, DMODEL, in_w_bf, DMODEL, xz_bf, 2 * DINNER, DMODEL, nullptr, nullptr, 0);

    conv_silu_k<<<dim3((LSEQ * DINNER) / 256, 2), blk, 0, stream>>>(
        xz_bf, cfw, cfb, cbw, cbb, xf_bf, xb_bf);

    thin_gemm_k<<<dim3(LSEQ / TG_R, TG_KS, 2), blk, 0, stream>>>(
        xf_bf, xb_bf, xfw, xbw, dbc_part);
    reduce_dbc_k<<<dim3((LSEQ * DBC) / 256, 2), blk, 0, stream>>>(
        dbc_part, dbcf, dbcb);

    delta_gemm_k<<<dim3(DINNER / BN, LSEQ / BM, 2), blk, 0, stream>>>(
        dbcf, dbcb, dfw, dbw, dfb, dbb, delf_bf, delb_bf);

    scan_a_k<<<dim3(DINNER / SCW, NQ - 1, 2), blk, 0, stream>>>(
        xf_bf, xb_bf, delf_bf, delb_bf, dbcf, dbcb, Af, Ab, qsP, qsQ);
    scan_c_k<<<dim3(DINNER / SCW, NQ, 2), blk, 0, stream>>>(
        xf_bf, xb_bf, delf_bf, delb_bf, dbcf, dbcb, Af, Ab, Df, Db, qsP, qsQ, ycat_bf);

    mgemmW_k<9><<<dim3(DINNER / 128, LSEQ / 64), blk, 0, stream>>>(
        ycat_bf, 2 * DINNER, pw_bf, 2 * DINNER, ypro_bf, DINNER, 2 * DINNER,
        pb, nullptr, 0);

    svgemm_k<<<640, blk, 0, stream>>>(wA_bf, ypro_bf, wVT_bf, Smat, vvT_bf);
    softmax_k<<<LSEQ, blk, 0, stream>>>(Smat, Smat_bf);

    mgemmW_k<56><<<dim3(DINNER / 128, LSEQ / 64), blk, 0, stream>>>(
        Smat_bf, LSEQ, vvT_bf, LSEQ, g_bf, DINNER, LSEQ,
        nullptr, (const float*)(xz_bf + DINNER), 2 * DINNER);

    float* target = (layer == NLAYER - 1) ? (float*)d_out : xbuf;
    mgemm_k<4><<<dim3(DMODEL / 64, LSEQ / 64), blk, 0, stream>>>(
        g_bf, DINNER, ow_bf, DINNER, target, DMODEL, DINNER,
        nullptr, xsrc, DMODEL);
  }
}

// Round 19
// 387.136 us; speedup vs baseline: 1.0741x; 1.0293x over previous
//
#include <hip/hip_runtime.h>
#include <hip/hip_bf16.h>
#include <math.h>
#include <stdint.h>

#define LSEQ 1024
#define DMODEL 768
#define DINNER 1536
#define DSTATE 16
#define DRANK 48
#define KCONV 4
#define NLAYER 2
#define DBC 80  // DRANK + 2*DSTATE
#define NQ 8            // L-split for the 3-phase scan
#define QL (LSEQ / NQ)  // 128
#define SCH 8           // chunks per scan block
#define SCW 32          // channels per scan block (32*2B = full 64B line)
#define QCH (QL / SCH)  // 16 steps per chunk

typedef unsigned short u16;
typedef __attribute__((ext_vector_type(8))) __bf16 bf16x8;
typedef __attribute__((ext_vector_type(4))) float f32x4;
typedef __attribute__((ext_vector_type(4))) unsigned short us4;  // 4 u16 = 8 B

__device__ __forceinline__ u16 f2bf(float f) {
  union { float f; unsigned u; } v; v.f = f;
  unsigned r = v.u + 0x7fffu + ((v.u >> 16) & 1u);  // RNE
  return (u16)(r >> 16);
}
__device__ __forceinline__ float bf2f(u16 u) {
  union { unsigned u; float f; } v; v.u = ((unsigned)u) << 16;
  return v.f;
}

// CK-style addrspace casts for global_load_lds (direct HBM->LDS DMA, 16B/lane)
__device__ __forceinline__ void gload16(const void* g, void* l) {
  auto gp = reinterpret_cast<const __attribute__((address_space(1))) uint32_t*>(
      reinterpret_cast<uintptr_t>(g));
  auto lp = reinterpret_cast<__attribute__((address_space(3))) uint32_t*>(
      reinterpret_cast<uintptr_t>(l));
  __builtin_amdgcn_global_load_lds(gp, lp, 16, 0, 0);
}

// ------------- fused fp32 -> bf16 convert of 4 weight mats, BOTH layers ------
#define CV0 589824              // 3072*768/4
#define CV1 (CV0 + 1179648)     // +1536*3072/4
#define CV2 (CV1 + 393216)      // +1024*1536/4
#define CV3 (CV2 + 294912)      // +768*1536/4 = 2457600 total float4s
#define WBL 12189696            // per-layer bf16 weight region (u16 elems)
__global__ __launch_bounds__(256) void cvt4_k(
    const float* __restrict__ i0, u16* __restrict__ o0, int s0o,
    const float* __restrict__ i1, u16* __restrict__ o1, int s1o,
    const float* __restrict__ i2, u16* __restrict__ o2, int s2o,
    const float* __restrict__ i3, u16* __restrict__ o3, int s3o) {
  int i = blockIdx.x * 256 + threadIdx.x;
  int lay = blockIdx.y;
  const float* in; u16* out; int off;
  if (i < CV0)      { in = i0 + (size_t)lay * s0o * 4; out = o0 + (size_t)lay * WBL; off = i; }
  else if (i < CV1) { in = i1 + (size_t)lay * s1o * 4; out = o1 + (size_t)lay * WBL; off = i - CV0; }
  else if (i < CV2) { in = i2 + (size_t)lay * s2o * 4; out = o2 + (size_t)lay * WBL; off = i - CV1; }
  else              { in = i3 + (size_t)lay * s3o * 4; out = o3 + (size_t)lay * WBL; off = i - CV2; }
  float4 v = ((const float4*)in)[off];
  us4 o; o[0] = f2bf(v.x); o[1] = f2bf(v.y); o[2] = f2bf(v.z); o[3] = f2bf(v.w);
  ((us4*)out)[off] = o;
}

// ---------------- fp32 -> bf16 transpose-convert (both layers via z) ---------
__global__ __launch_bounds__(256) void transcvt_k(const float* __restrict__ in0,
                                                  u16* __restrict__ out0,
                                                  int R, int C) {
  __shared__ float t[32][33];
  const float* in = in0 + (size_t)blockIdx.z * R * C;
  u16* out = out0 + (size_t)blockIdx.z * WBL;
  int c0 = blockIdx.x * 32, r0 = blockIdx.y * 32;
  int tx = threadIdx.x & 31, ty = threadIdx.x >> 5;
  for (int i = ty; i < 32; i += 8) t[i][tx] = in[(size_t)(r0 + i) * C + c0 + tx];
  __syncthreads();
  for (int i = ty; i < 32; i += 8)
    out[(size_t)(c0 + i) * R + r0 + tx] = f2bf(t[tx][i]);
}

// ---------------- rmsnorm (bf16 out) ----------------
__global__ __launch_bounds__(256) void rmsnorm_k(const float* __restrict__ x,
                                                 const float* __restrict__ w,
                                                 u16* __restrict__ xn) {
  int row = blockIdx.x;
  int tid = threadIdx.x;
  const float* xr = x + (size_t)row * DMODEL;
  float ss = 0.f;
  for (int j = tid; j < DMODEL; j += 256) { float v = xr[j]; ss += v * v; }
  __shared__ float red[256];
  red[tid] = ss; __syncthreads();
  for (int s = 128; s > 0; s >>= 1) { if (tid < s) red[tid] += red[tid + s]; __syncthreads(); }
  float scale = rsqrtf(red[0] / (float)DMODEL + 1e-5f);
  u16* outr = xn + (size_t)row * DMODEL;
  for (int j = tid; j < DMODEL; j += 256) outr[j] = f2bf(xr[j] * scale * w[j]);
}

// ---------------- MFMA bf16 GEMM: 64x64 tile -------------
// EPI bit0: +bias; bit2: +resid fp32; bit3: bf16 out; bit4: *silu(resid);
// bit5: resid is bf16.
template<int EPI>
__global__ __launch_bounds__(256) void mgemm_k(
    const u16* __restrict__ A, int lda,
    const u16* __restrict__ B, int ldb,
    void* __restrict__ Cv, int ldc, int K,
    const float* __restrict__ bias,
    const float* __restrict__ resid, int ldr)
{
  __shared__ u16 As[2][64 * 64];
  __shared__ u16 Bs[2][64 * 64];
  const int tid = threadIdx.x;
  const int lane = tid & 63;
  const int w = tid >> 6;

  const int nbx = gridDim.x;
  int bid = blockIdx.y * nbx + blockIdx.x;
  const int nwg = nbx * gridDim.y;
  bid = (bid & 7) * (nwg >> 3) + (bid >> 3);
  const int bm = (bid / nbx) * 64;
  const int bn = (bid % nbx) * 64;

  const int srow = lane >> 3;
  const int scs = (lane & 7) ^ srow;
  const int gA = 2 * w;
  const u16* Asrc0 = A + (size_t)(bm + gA * 8 + srow) * lda + scs * 8;
  const u16* Asrc1 = Asrc0 + (size_t)8 * lda;
  const u16* Bsrc0 = B + (size_t)(bn + gA * 8 + srow) * ldb + scs * 8;
  const u16* Bsrc1 = Bsrc0 + (size_t)8 * ldb;
  const int d0 = gA * 512;
  const int d1 = d0 + 512;

  const int fr = lane & 15;
  const int fs = lane >> 4;
  const int wm = (w >> 1) * 32;
  const int wn = (w & 1) * 32;
  int aoff[2][2], boff[2][2];
#pragma unroll
  for (int i = 0; i < 2; i++)
#pragma unroll
    for (int h = 0; h < 2; h++) {
      const int g = h * 4 + fs;
      aoff[i][h] = (wm + i * 16 + fr) * 64 + (g ^ (fr & 7)) * 8;
      boff[i][h] = (wn + i * 16 + fr) * 64 + (g ^ (fr & 7)) * 8;
    }

  f32x4 acc[2][2];
#pragma unroll
  for (int i = 0; i < 2; i++)
#pragma unroll
    for (int j = 0; j < 2; j++) acc[i][j] = (f32x4){0.f, 0.f, 0.f, 0.f};

#define STAGE(buf, k0) do { \
    gload16(Asrc0 + (k0), &As[buf][d0]); \
    gload16(Asrc1 + (k0), &As[buf][d1]); \
    gload16(Bsrc0 + (k0), &Bs[buf][d0]); \
    gload16(Bsrc1 + (k0), &Bs[buf][d1]); \
  } while (0)

  const int nk = K >> 6;
  STAGE(0, 0);

  for (int t = 0; t < nk; t++) {
    const int buf = t & 1;
    __syncthreads();
    if (t + 1 < nk) STAGE(buf ^ 1, (t + 1) << 6);
    const u16* As_ = As[buf];
    const u16* Bs_ = Bs[buf];
#pragma unroll
    for (int h = 0; h < 2; h++) {
      bf16x8 a0 = *reinterpret_cast<const bf16x8*>(As_ + aoff[0][h]);
      bf16x8 a1 = *reinterpret_cast<const bf16x8*>(As_ + aoff[1][h]);
      bf16x8 b0 = *reinterpret_cast<const bf16x8*>(Bs_ + boff[0][h]);
      bf16x8 b1 = *reinterpret_cast<const bf16x8*>(Bs_ + boff[1][h]);
      acc[0][0] = __builtin_amdgcn_mfma_f32_16x16x32_bf16(a0, b0, acc[0][0], 0, 0, 0);
      acc[0][1] = __builtin_amdgcn_mfma_f32_16x16x32_bf16(a0, b1, acc[0][1], 0, 0, 0);
      acc[1][0] = __builtin_amdgcn_mfma_f32_16x16x32_bf16(a1, b0, acc[1][0], 0, 0, 0);
      acc[1][1] = __builtin_amdgcn_mfma_f32_16x16x32_bf16(a1, b1, acc[1][1], 0, 0, 0);
    }
  }
#undef STAGE

#pragma unroll
  for (int i = 0; i < 2; i++) {
#pragma unroll
    for (int j = 0; j < 2; j++) {
      const int col = bn + wn + j * 16 + fr;
      const int row0 = bm + wm + i * 16 + fs * 4;
      float bv = (EPI & 1) ? bias[col] : 0.f;
#pragma unroll
      for (int r = 0; r < 4; r++) {
        float v = acc[i][j][r] + bv;
        if (EPI & 4) v += resid[(size_t)(row0 + r) * ldr + col];
        if (EPI & 16) {
          float z = (EPI & 32)
              ? bf2f(((const u16*)resid)[(size_t)(row0 + r) * ldr + col])
              : resid[(size_t)(row0 + r) * ldr + col];
          v *= z / (1.f + __expf(-z));
        }
        if (EPI & 8) ((u16*)Cv)[(size_t)(row0 + r) * ldc + col] = f2bf(v);
        else         ((float*)Cv)[(size_t)(row0 + r) * ldc + col] = v;
      }
    }
  }
}

// ------- MFMA bf16 GEMM: 64x128 tile (xz only; grid stays >= 384) ------------
template<int EPI>
__global__ __launch_bounds__(256) void mgemmW_k(
    const u16* __restrict__ A, int lda,
    const u16* __restrict__ B, int ldb,
    void* __restrict__ Cv, int ldc, int K,
    const float* __restrict__ bias,
    const float* __restrict__ resid, int ldr)
{
  __shared__ u16 As[2][64 * 64];
  __shared__ u16 Bs[2][128 * 64];
  const int tid = threadIdx.x;
  const int lane = tid & 63;
  const int w = tid >> 6;

  const int nbx = gridDim.x;
  int bid = blockIdx.y * nbx + blockIdx.x;
  const int nwg = nbx * gridDim.y;
  bid = (bid & 7) * (nwg >> 3) + (bid >> 3);
  const int bm = (bid / nbx) * 64;
  const int bn = (bid % nbx) * 128;

  const int srow = lane >> 3;
  const int scs = (lane & 7) ^ srow;
  const u16* Asrc0 = A + (size_t)(bm + (2 * w) * 8 + srow) * lda + scs * 8;
  const u16* Asrc1 = Asrc0 + (size_t)8 * lda;
  const int da0 = (2 * w) * 512, da1 = da0 + 512;
  const u16* Bsrc0 = B + (size_t)(bn + (4 * w) * 8 + srow) * ldb + scs * 8;
  const u16* Bsrc1 = Bsrc0 + (size_t)8 * ldb;
  const u16* Bsrc2 = Bsrc1 + (size_t)8 * ldb;
  const u16* Bsrc3 = Bsrc2 + (size_t)8 * ldb;
  const int db0 = (4 * w) * 512;

  const int fr = lane & 15;
  const int fs = lane >> 4;
  const int wm = (w >> 1) * 32;
  const int wn = (w & 1) * 64;
  int aoff[2][2], boff[4][2];
#pragma unroll
  for (int h = 0; h < 2; h++) {
    const int g = h * 4 + fs;
    const int sw = (g ^ (fr & 7)) * 8;
#pragma unroll
    for (int i = 0; i < 2; i++) aoff[i][h] = (wm + i * 16 + fr) * 64 + sw;
#pragma unroll
    for (int j = 0; j < 4; j++) boff[j][h] = (wn + j * 16 + fr) * 64 + sw;
  }

  f32x4 acc[2][4];
#pragma unroll
  for (int i = 0; i < 2; i++)
#pragma unroll
    for (int j = 0; j < 4; j++) acc[i][j] = (f32x4){0.f, 0.f, 0.f, 0.f};

#define STAGEW(buf, k0) do { \
    gload16(Asrc0 + (k0), &As[buf][da0]); \
    gload16(Asrc1 + (k0), &As[buf][da1]); \
    gload16(Bsrc0 + (k0), &Bs[buf][db0]); \
    gload16(Bsrc1 + (k0), &Bs[buf][db0 + 512]); \
    gload16(Bsrc2 + (k0), &Bs[buf][db0 + 1024]); \
    gload16(Bsrc3 + (k0), &Bs[buf][db0 + 1536]); \
  } while (0)

  const int nk = K >> 6;
  STAGEW(0, 0);

  for (int t = 0; t < nk; t++) {
    const int buf = t & 1;
    __syncthreads();
    if (t + 1 < nk) STAGEW(buf ^ 1, (t + 1) << 6);
    const u16* As_ = As[buf];
    const u16* Bs_ = Bs[buf];
#pragma unroll
    for (int h = 0; h < 2; h++) {
      bf16x8 a0 = *reinterpret_cast<const bf16x8*>(As_ + aoff[0][h]);
      bf16x8 a1 = *reinterpret_cast<const bf16x8*>(As_ + aoff[1][h]);
#pragma unroll
      for (int j = 0; j < 4; j++) {
        bf16x8 b = *reinterpret_cast<const bf16x8*>(Bs_ + boff[j][h]);
        acc[0][j] = __builtin_amdgcn_mfma_f32_16x16x32_bf16(a0, b, acc[0][j], 0, 0, 0);
        acc[1][j] = __builtin_amdgcn_mfma_f32_16x16x32_bf16(a1, b, acc[1][j], 0, 0, 0);
      }
    }
  }
#undef STAGEW

#pragma unroll
  for (int i = 0; i < 2; i++) {
#pragma unroll
    for (int j = 0; j < 4; j++) {
      const int col = bn + wn + j * 16 + fr;
      const int row0 = bm + wm + i * 16 + fs * 4;
      float bv = (EPI & 1) ? bias[col] : 0.f;
#pragma unroll
      for (int r = 0; r < 4; r++) {
        float v = acc[i][j][r] + bv;
        if (EPI & 4) v += resid[(size_t)(row0 + r) * ldr + col];
        if (EPI & 16) {
          float z = (EPI & 32)
              ? bf2f(((const u16*)resid)[(size_t)(row0 + r) * ldr + col])
              : resid[(size_t)(row0 + r) * ldr + col];
          v *= z / (1.f + __expf(-z));
        }
        if (EPI & 8) ((u16*)Cv)[(size_t)(row0 + r) * ldc + col] = f2bf(v);
        else         ((float*)Cv)[(size_t)(row0 + r) * ldc + col] = v;
      }
    }
  }
}

// ---------------- fused S + vv GEMM; vv part writes vvT directly -------------
__global__ __launch_bounds__(256) void svgemm_k(
    const u16* __restrict__ wA, const u16* __restrict__ ypro,
    const u16* __restrict__ wVT,
    float* __restrict__ Smat, u16* __restrict__ vvT)
{
  __shared__ u16 As[2][64 * 64];
  __shared__ u16 Bs[2][64 * 64];
  __shared__ u16 tr[4][32][33];
  const int tid = threadIdx.x;
  const int lane = tid & 63;
  const int w = tid >> 6;

  int bid = blockIdx.x;
  bid = (bid & 7) * 80 + (bid >> 3);
  const bool is_s = bid < 256;
  const u16* A;
  const u16* B;
  int bm, bn;
  if (is_s) { A = wA;   B = ypro; bm = (bid >> 4) * 64;         bn = (bid & 15) * 64; }
  else      { A = ypro; B = wVT;  bm = ((bid - 256) / 24) * 64; bn = ((bid - 256) % 24) * 64; }

  const int srow = lane >> 3;
  const int scs = (lane & 7) ^ srow;
  const int gA = 2 * w;
  const u16* Asrc0 = A + (size_t)(bm + gA * 8 + srow) * DINNER + scs * 8;
  const u16* Asrc1 = Asrc0 + (size_t)8 * DINNER;
  const u16* Bsrc0 = B + (size_t)(bn + gA * 8 + srow) * DINNER + scs * 8;
  const u16* Bsrc1 = Bsrc0 + (size_t)8 * DINNER;
  const int d0 = gA * 512;
  const int d1 = d0 + 512;

  const int fr = lane & 15;
  const int fs = lane >> 4;
  const int wm = (w >> 1) * 32;
  const int wn = (w & 1) * 32;
  int aoff[2][2], boff[2][2];
#pragma unroll
  for (int i = 0; i < 2; i++)
#pragma unroll
    for (int h = 0; h < 2; h++) {
      const int g = h * 4 + fs;
      aoff[i][h] = (wm + i * 16 + fr) * 64 + (g ^ (fr & 7)) * 8;
      boff[i][h] = (wn + i * 16 + fr) * 64 + (g ^ (fr & 7)) * 8;
    }

  f32x4 acc[2][2];
#pragma unroll
  for (int i = 0; i < 2; i++)
#pragma unroll
    for (int j = 0; j < 2; j++) acc[i][j] = (f32x4){0.f, 0.f, 0.f, 0.f};

#define STAGE(buf, k0) do { \
    gload16(Asrc0 + (k0), &As[buf][d0]); \
    gload16(Asrc1 + (k0), &As[buf][d1]); \
    gload16(Bsrc0 + (k0), &Bs[buf][d0]); \
    gload16(Bsrc1 + (k0), &Bs[buf][d1]); \
  } while (0)

  STAGE(0, 0);
  for (int t = 0; t < DINNER / 64; t++) {
    const int buf = t & 1;
    __syncthreads();
    if (t + 1 < DINNER / 64) STAGE(buf ^ 1, (t + 1) << 6);
    const u16* As_ = As[buf];
    const u16* Bs_ = Bs[buf];
#pragma unroll
    for (int h = 0; h < 2; h++) {
      bf16x8 a0 = *reinterpret_cast<const bf16x8*>(As_ + aoff[0][h]);
      bf16x8 a1 = *reinterpret_cast<const bf16x8*>(As_ + aoff[1][h]);
      bf16x8 b0 = *reinterpret_cast<const bf16x8*>(Bs_ + boff[0][h]);
      bf16x8 b1 = *reinterpret_cast<const bf16x8*>(Bs_ + boff[1][h]);
      acc[0][0] = __builtin_amdgcn_mfma_f32_16x16x32_bf16(a0, b0, acc[0][0], 0, 0, 0);
      acc[0][1] = __builtin_amdgcn_mfma_f32_16x16x32_bf16(a0, b1, acc[0][1], 0, 0, 0);
      acc[1][0] = __builtin_amdgcn_mfma_f32_16x16x32_bf16(a1, b0, acc[1][0], 0, 0, 0);
      acc[1][1] = __builtin_amdgcn_mfma_f32_16x16x32_bf16(a1, b1, acc[1][1], 0, 0, 0);
    }
  }
#undef STAGE

  if (is_s) {
#pragma unroll
    for (int i = 0; i < 2; i++)
#pragma unroll
      for (int j = 0; j < 2; j++) {
        const int col = bn + wn + j * 16 + fr;
        const int row0 = bm + wm + i * 16 + fs * 4;
#pragma unroll
        for (int r = 0; r < 4; r++)
          Smat[(size_t)(row0 + r) * LSEQ + col] = acc[i][j][r];
      }
  } else {
#pragma unroll
    for (int i = 0; i < 2; i++)
#pragma unroll
      for (int j = 0; j < 2; j++) {
        const int lr0 = i * 16 + fs * 4;
        const int lc = j * 16 + fr;
#pragma unroll
        for (int r = 0; r < 4; r++) tr[w][lr0 + r][lc] = f2bf(acc[i][j][r]);
      }
    __syncthreads();
    const int lc = lane >> 1;
    const int half = lane & 1;
    const int gcol = bn + wn + lc;
    const int grow0 = bm + wm + half * 16;
    u16* dst = vvT + (size_t)gcol * LSEQ + grow0;
#pragma unroll
    for (int q = 0; q < 4; q++) {
      us4 v;
#pragma unroll
      for (int e = 0; e < 4; e++) v[e] = tr[w][half * 16 + q * 4 + e][lc];
      *(us4*)(dst + q * 4) = v;
    }
  }
}

// ---------------- thin dbc GEMM (bf16 A, f+b merged) -------------------------
#define TG_R 16
#define TG_KC 96
#define TG_KS 16

__global__ __launch_bounds__(256) void thin_gemm_k(
    const u16* __restrict__ Af_, const u16* __restrict__ Ab_,
    const float* __restrict__ Bf_, const float* __restrict__ Bb_,
    float* __restrict__ partial)
{
  __shared__ u16 As[TG_R][TG_KC];
  __shared__ float Bs[80][100];
  const u16* A = blockIdx.z ? Ab_ : Af_;
  const float* B = blockIdx.z ? Bb_ : Bf_;
  float* part = partial + (size_t)blockIdx.z * TG_KS * LSEQ * DBC;
  const int tid = threadIdx.x;
  const int m0 = blockIdx.x * TG_R;
  const int ks = blockIdx.y;
  const int k0 = ks * TG_KC;

  for (int i = tid; i < 384; i += 256) {
    int r = i / 24, q = i % 24;
    *(us4*)&As[r][q * 4] = *(const us4*)(A + (size_t)(m0 + r) * DINNER + k0 + q * 4);
  }
  for (int i = tid; i < 1920; i += 256) {
    int r = i / 24, q = i % 24;
    *(float4*)&Bs[r][q * 4] = *(const float4*)(B + (size_t)r * DINNER + k0 + q * 4);
  }
  __syncthreads();

  const int r = tid >> 4;
  const int c0 = (tid & 15) * 5;
  float acc[5] = {};
  for (int k = 0; k < TG_KC; k++) {
    float a = bf2f(As[r][k]);
#pragma unroll
    for (int j = 0; j < 5; j++) acc[j] += a * Bs[c0 + j][k];
  }
  float* out = part + ((size_t)ks * LSEQ + m0 + r) * DBC + c0;
#pragma unroll
  for (int j = 0; j < 5; j++) out[j] = acc[j];
}

__global__ __launch_bounds__(256) void reduce_dbc_k(const float* __restrict__ partial,
                                                    float* __restrict__ outf,
                                                    float* __restrict__ outb) {
  int i = blockIdx.x * 256 + threadIdx.x;
  const float* part = partial + (size_t)blockIdx.y * TG_KS * LSEQ * DBC;
  float s = 0.f;
#pragma unroll
  for (int ks = 0; ks < TG_KS; ks++) s += part[(size_t)ks * (LSEQ * DBC) + i];
  (blockIdx.y ? outb : outf)[i] = s;
}

// ---------------- delta = softplus(dlt @ dt_w^T + dt_b), f+b merged, bf16 out
#define BM 64
#define BN 64
#define BK 16

__global__ __launch_bounds__(256) void delta_gemm_k(
    const float* __restrict__ A0, const float* __restrict__ A1,
    const float* __restrict__ B0, const float* __restrict__ B1,
    const float* __restrict__ b0, const float* __restrict__ b1,
    u16* __restrict__ C0, u16* __restrict__ C1)
{
  __shared__ float Asf[BK][BM];
  __shared__ float Bsf[BK][BN + 4];
  const float* A = blockIdx.z ? A1 : A0;
  const float* B = blockIdx.z ? B1 : B0;
  const float* bias = blockIdx.z ? b1 : b0;
  u16* C = blockIdx.z ? C1 : C0;
  const int tid = threadIdx.x;
  const int bm = blockIdx.y * BM;
  const int bn = blockIdx.x * BN;
  const int ar = tid >> 2;
  const int ak = (tid & 3) << 2;
  const int ty = tid >> 4, tx = tid & 15;
  float acc[4][4] = {};

  for (int k0 = 0; k0 < DRANK; k0 += BK) {
    float4 av = *(const float4*)(A + (size_t)(bm + ar) * DBC + k0 + ak);
    float4 bv = *(const float4*)(B + (size_t)(bn + ar) * DRANK + k0 + ak);
    __syncthreads();
    Asf[ak + 0][ar] = av.x; Asf[ak + 1][ar] = av.y;
    Asf[ak + 2][ar] = av.z; Asf[ak + 3][ar] = av.w;
    Bsf[ak + 0][ar] = bv.x; Bsf[ak + 1][ar] = bv.y;
    Bsf[ak + 2][ar] = bv.z; Bsf[ak + 3][ar] = bv.w;
    __syncthreads();
#pragma unroll
    for (int kk = 0; kk < BK; kk++) {
      float4 a4 = *(const float4*)&Asf[kk][ty * 4];
      float4 b4 = *(const float4*)&Bsf[kk][tx * 4];
      float a[4] = {a4.x, a4.y, a4.z, a4.w};
      float b[4] = {b4.x, b4.y, b4.z, b4.w};
#pragma unroll
      for (int i = 0; i < 4; i++)
#pragma unroll
        for (int j = 0; j < 4; j++)
          acc[i][j] += a[i] * b[j];
    }
  }

#pragma unroll
  for (int i = 0; i < 4; i++) {
    int row = bm + ty * 4 + i;
#pragma unroll
    for (int j = 0; j < 4; j++) {
      int col = bn + tx * 4 + j;
      float v = acc[i][j] + bias[col];
      v = (v > 20.f) ? v : log1pf(__expf(v));
      C[(size_t)row * DINNER + col] = f2bf(v);
    }
  }
}

// ---------------- causal depthwise conv + silu (bf16 in/out, both dirs) ------
__global__ __launch_bounds__(256) void conv_silu_k(
    const u16* __restrict__ xz,
    const float* __restrict__ wf, const float* __restrict__ bf,
    const float* __restrict__ wb, const float* __restrict__ bb,
    u16* __restrict__ xf, u16* __restrict__ xb)
{
  int idx = blockIdx.x * 256 + threadIdx.x;
  int dir = blockIdx.y;
  if (idx >= LSEQ * DINNER) return;
  int l = idx / DINNER, c = idx % DINNER;
  const float* w = (dir ? wb : wf) + c * KCONV;
  float acc = (dir ? bb : bf)[c];
#pragma unroll
  for (int k = 0; k < KCONV; k++) {
    int ls = l - (KCONV - 1) + k;
    if (ls >= 0) {
      int lsrc = dir ? (LSEQ - 1 - ls) : ls;
      acc += w[k] * bf2f(xz[(size_t)lsrc * (2 * DINNER) + c]);
    }
  }
  float sv = acc / (1.f + __expf(-acc));
  (dir ? xb : xf)[idx] = f2bf(sv);
}

// ---------------- 3-phase L-split scan (fast-exp) ----------------------------
// FAST-EXP: A_log = log(1..16) in this model, so Aa[s] = Aa0*(s+1) and
// exp(dt*Aa[s]) = exp(dt*Aa0)^(s+1) — 1 exp + 15 muls instead of 16 exps.
// Verified per-thread with rel tol 1e-4; generic exp fallback otherwise.
__global__ __launch_bounds__(256) void scan_a_k(
    const u16* __restrict__ xcf, const u16* __restrict__ xcb,
    const u16* __restrict__ dltf, const u16* __restrict__ dltb,
    const float* __restrict__ dbcf, const float* __restrict__ dbcb,
    const float* __restrict__ Af, const float* __restrict__ Ab,
    float* __restrict__ qsP, float* __restrict__ qsQ)
{
  __shared__ float sP[SCH * SCW * DSTATE];
  __shared__ float sQ[SCH * SCW * DSTATE];
  const int dir = blockIdx.z;
  const int qid = blockIdx.y;   // 0..NQ-2 (last octave's summary never used)
  const u16*   xc    = dir ? xcb : xcf;
  const u16*   delta = dir ? dltb : dltf;
  const float* dbc   = dir ? dbcb : dbcf;
  const float* A_log = dir ? Ab : Af;

  const int tid = threadIdx.x;
  const int c = tid >> 5;
  const int dl = tid & 31;
  const int d = blockIdx.x * SCW + dl;

  float Aa[DSTATE];
#pragma unroll
  for (int s = 0; s < DSTATE; s++) Aa[s] = -__expf(A_log[(size_t)d * DSTATE + s]);
  const float Aa0 = Aa[0];
  bool fast = true;
#pragma unroll
  for (int s = 1; s < DSTATE; s++)
    fast = fast && (fabsf(Aa[s] - Aa0 * (float)(s + 1)) <= 1e-4f * fabsf(Aa[s]));

  float aP[DSTATE], q[DSTATE];
#pragma unroll
  for (int s = 0; s < DSTATE; s++) { aP[s] = 1.f; q[s] = 0.f; }
  const int l0 = qid * QL + c * QCH;
  if (fast) {
    for (int i = 0; i < QCH; i++) {
      int l = l0 + i;
      float dt = bf2f(delta[(size_t)l * DINNER + d]);
      float dx = dt * bf2f(xc[(size_t)l * DINNER + d]);
      const float* bm = dbc + (size_t)l * DBC + DRANK;
      float e0 = __expf(dt * Aa0);
      float a = 1.f;
#pragma unroll
      for (int s = 0; s < DSTATE; s++) {
        a *= e0;
        q[s] = a * q[s] + dx * bm[s];
        aP[s] *= a;
      }
    }
  } else {
    for (int i = 0; i < QCH; i++) {
      int l = l0 + i;
      float dt = bf2f(delta[(size_t)l * DINNER + d]);
      float dx = dt * bf2f(xc[(size_t)l * DINNER + d]);
      const float* bm = dbc + (size_t)l * DBC + DRANK;
#pragma unroll
      for (int s = 0; s < DSTATE; s++) {
        float a = __expf(dt * Aa[s]);
        q[s] = a * q[s] + dx * bm[s];
        aP[s] *= a;
      }
    }
  }
#pragma unroll
  for (int s = 0; s < DSTATE; s++) {
    sP[(c * SCW + dl) * DSTATE + s] = aP[s];
    sQ[(c * SCW + dl) * DSTATE + s] = q[s];
  }
  __syncthreads();

#pragma unroll
  for (int pp = 0; pp < 2; pp++) {
    const int p = tid + pp * 256;
    const int d2 = p >> 4, s2 = p & 15;
    float h = 0.f, P = 1.f;
    for (int cc = 0; cc < SCH; cc++) {
      int idx = (cc * SCW + d2) * DSTATE + s2;
      h = sP[idx] * h + sQ[idx];
      P *= sP[idx];
    }
    size_t o = (((size_t)dir * NQ + qid) * DINNER + blockIdx.x * SCW + d2) * DSTATE + s2;
    qsP[o] = P;
    qsQ[o] = h;
  }
}

__global__ __launch_bounds__(256) void scan_c_k(
    const u16* __restrict__ xcf, const u16* __restrict__ xcb,
    const u16* __restrict__ dltf, const u16* __restrict__ dltb,
    const float* __restrict__ dbcf, const float* __restrict__ dbcb,
    const float* __restrict__ Af, const float* __restrict__ Ab,
    const float* __restrict__ Df, const float* __restrict__ Db,
    const float* __restrict__ qsP, const float* __restrict__ qsQ,
    u16* __restrict__ ycat)
{
  __shared__ float sP[SCH * SCW * DSTATE];
  __shared__ float sQ[SCH * SCW * DSTATE];
  const int dir = blockIdx.z;
  const int qid = blockIdx.y;
  const u16*   xc    = dir ? xcb : xcf;
  const u16*   delta = dir ? dltb : dltf;
  const float* dbc   = dir ? dbcb : dbcf;
  const float* A_log = dir ? Ab : Af;
  const float* Dvec  = dir ? Db : Df;
  const int col_off  = dir ? DINNER : 0;

  const int tid = threadIdx.x;
  const int c = tid >> 5;
  const int dl = tid & 31;
  const int d = blockIdx.x * SCW + dl;

  float Aa[DSTATE];
#pragma unroll
  for (int s = 0; s < DSTATE; s++) Aa[s] = -__expf(A_log[(size_t)d * DSTATE + s]);
  const float Aa0 = Aa[0];
  bool fast = true;
#pragma unroll
  for (int s = 1; s < DSTATE; s++)
    fast = fast && (fabsf(Aa[s] - Aa0 * (float)(s + 1)) <= 1e-4f * fabsf(Aa[s]));

  float aP[DSTATE], q[DSTATE];
#pragma unroll
  for (int s = 0; s < DSTATE; s++) { aP[s] = 1.f; q[s] = 0.f; }
  const int l0 = qid * QL + c * QCH;
  if (fast) {
    for (int i = 0; i < QCH; i++) {
      int l = l0 + i;
      float dt = bf2f(delta[(size_t)l * DINNER + d]);
      float dx = dt * bf2f(xc[(size_t)l * DINNER + d]);
      const float* bm = dbc + (size_t)l * DBC + DRANK;
      float e0 = __expf(dt * Aa0);
      float a = 1.f;
#pragma unroll
      for (int s = 0; s < DSTATE; s++) {
        a *= e0;
        q[s] = a * q[s] + dx * bm[s];
        aP[s] *= a;
      }
    }
  } else {
    for (int i = 0; i < QCH; i++) {
      int l = l0 + i;
      float dt = bf2f(delta[(size_t)l * DINNER + d]);
      float dx = dt * bf2f(xc[(size_t)l * DINNER + d]);
      const float* bm = dbc + (size_t)l * DBC + DRANK;
#pragma unroll
      for (int s = 0; s < DSTATE; s++) {
        float a = __expf(dt * Aa[s]);
        q[s] = a * q[s] + dx * bm[s];
        aP[s] *= a;
      }
    }
  }
#pragma unroll
  for (int s = 0; s < DSTATE; s++) {
    sP[(c * SCW + dl) * DSTATE + s] = aP[s];
    sQ[(c * SCW + dl) * DSTATE + s] = q[s];
  }
  __syncthreads();

#pragma unroll
  for (int pp = 0; pp < 2; pp++) {
    const int p = tid + pp * 256;
    const int d2 = p >> 4, s2 = p & 15;
    float h = 0.f;
    for (int qq = 0; qq < qid; qq++) {
      size_t o = (((size_t)dir * NQ + qq) * DINNER + blockIdx.x * SCW + d2) * DSTATE + s2;
      h = qsP[o] * h + qsQ[o];
    }
    for (int cc = 0; cc < SCH; cc++) {
      int idx = (cc * SCW + d2) * DSTATE + s2;
      float a = sP[idx], qv = sQ[idx];
      sP[idx] = h;
      h = a * h + qv;
    }
  }
  __syncthreads();

  float hs[DSTATE];
#pragma unroll
  for (int s = 0; s < DSTATE; s++) hs[s] = sP[(c * SCW + dl) * DSTATE + s];
  const float Dd = Dvec[d];
  if (fast) {
    for (int i = 0; i < QCH; i++) {
      int l = l0 + i;
      float dt = bf2f(delta[(size_t)l * DINNER + d]);
      float xv = bf2f(xc[(size_t)l * DINNER + d]);
      float dx = dt * xv;
      const float* bm = dbc + (size_t)l * DBC + DRANK;
      const float* cm = bm + DSTATE;
      float e0 = __expf(dt * Aa0);
      float a = 1.f;
      float y = 0.f;
#pragma unroll
      for (int s = 0; s < DSTATE; s++) {
        a *= e0;
        hs[s] = a * hs[s] + dx * bm[s];
        y += hs[s] * cm[s];
      }
      ycat[(size_t)l * (2 * DINNER) + col_off + d] = f2bf(y + Dd * xv);
    }
  } else {
    for (int i = 0; i < QCH; i++) {
      int l = l0 + i;
      float dt = bf2f(delta[(size_t)l * DINNER + d]);
      float xv = bf2f(xc[(size_t)l * DINNER + d]);
      float dx = dt * xv;
      const float* bm = dbc + (size_t)l * DBC + DRANK;
      const float* cm = bm + DSTATE;
      float y = 0.f;
#pragma unroll
      for (int s = 0; s < DSTATE; s++) {
        float a = __expf(dt * Aa[s]);
        hs[s] = a * hs[s] + dx * bm[s];
        y += hs[s] * cm[s];
      }
      ycat[(size_t)l * (2 * DINNER) + col_off + d] = f2bf(y + Dd * xv);
    }
  }
}

// ---------------- row softmax (fp32 in, bf16 out) ----------------
__global__ __launch_bounds__(256) void softmax_k(const float* __restrict__ S,
                                                 u16* __restrict__ P) {
  int row = blockIdx.x, tid = threadIdx.x;
  __shared__ float buf[LSEQ];
  __shared__ float red[256];
  const float* r = S + (size_t)row * LSEQ;
  float m = -1e30f;
  for (int j = tid; j < LSEQ; j += 256) { float v = r[j]; buf[j] = v; m = fmaxf(m, v); }
  red[tid] = m; __syncthreads();
  for (int s = 128; s > 0; s >>= 1) { if (tid < s) red[tid] = fmaxf(red[tid], red[tid + s]); __syncthreads(); }
  m = red[0];
  __syncthreads();
  float sum = 0.f;
  for (int j = tid; j < LSEQ; j += 256) { float e = __expf(buf[j] - m); buf[j] = e; sum += e; }
  red[tid] = sum; __syncthreads();
  for (int s = 128; s > 0; s >>= 1) { if (tid < s) red[tid] += red[tid + s]; __syncthreads(); }
  float inv = 1.f / red[0];
  u16* pr = P + (size_t)row * LSEQ;
  for (int j = tid; j < LSEQ; j += 256) pr[j] = f2bf(buf[j] * inv);
}

extern "C" void kernel_launch(void* const* d_in, const int* in_sizes, int n_in,
                              void* d_out, int out_size, void* d_ws, size_t ws_size,
                              hipStream_t stream) {
  const float* in_x      = (const float*)d_in[0];
  const float* norm_w    = (const float*)d_in[1];
  const float* in_proj_w = (const float*)d_in[2];
  const float* conv_f_w  = (const float*)d_in[3];
  const float* conv_f_b  = (const float*)d_in[4];
  const float* conv_b_w  = (const float*)d_in[5];
  const float* conv_b_b  = (const float*)d_in[6];
  const float* xproj_f_w = (const float*)d_in[7];
  const float* xproj_b_w = (const float*)d_in[8];
  const float* dt_f_w    = (const float*)d_in[9];
  const float* dt_f_b    = (const float*)d_in[10];
  const float* dt_b_w    = (const float*)d_in[11];
  const float* dt_b_b    = (const float*)d_in[12];
  const float* A_log_f   = (const float*)d_in[13];
  const float* D_f       = (const float*)d_in[14];
  const float* A_log_b   = (const float*)d_in[15];
  const float* D_b       = (const float*)d_in[16];
  const float* out_w     = (const float*)d_in[17];
  const float* token_wA  = (const float*)d_in[18];
  const float* token_wV  = (const float*)d_in[19];
  const float* pro_w     = (const float*)d_in[20];
  const float* pro_b     = (const float*)d_in[21];

  // ---- workspace carve (fp32 units) ----
  float* ws = (float*)d_ws;
  float* xbuf = ws; ws += LSEQ * DMODEL;
  u16* xz_bf  = (u16*)ws; ws += LSEQ * DINNER;
  u16* xf_bf  = (u16*)ws; ws += (LSEQ * DINNER) / 2;
  u16* xb_bf  = (u16*)ws; ws += (LSEQ * DINNER) / 2;
  float* dbcf = ws; ws += LSEQ * DBC;
  float* dbcb = ws; ws += LSEQ * DBC;
  float* delf_r = ws; ws += LSEQ * DINNER;
  float* delb_r = ws; ws += LSEQ * DINNER;
  float* scr  = ws; ws += LSEQ * DINNER;
  u16* xn_bf   = (u16*)ws; ws += (LSEQ * DMODEL) / 2;
  u16* ycat_bf = (u16*)ws; ws += LSEQ * DINNER;
  u16* ypro_bf = (u16*)ws; ws += (LSEQ * DINNER) / 2;
  u16* Wb      = (u16*)ws;

  u16* in_w_bf0 = Wb;
  u16* pw_bf0   = in_w_bf0 + 3072 * 768;
  u16* wA_bf0   = pw_bf0 + 1536 * 3072;
  u16* wVT_bf0  = wA_bf0 + 1024 * 1536;
  u16* ow_bf0   = wVT_bf0 + 1536 * 1536;

  float* dbc_part = delf_r;
  u16*   delf_bf  = (u16*)delf_r;
  u16*   delb_bf  = (u16*)delb_r;
  float* Smat     = delf_r;
  u16*   Smat_bf  = (u16*)delb_r;
  u16*   vvT_bf   = xb_bf;        // xb dead after scan_c
  u16*   g_bf     = ypro_bf;
  const int QS = 2 * NQ * DINNER * DSTATE;
  float* qsP   = scr;
  float* qsQ   = scr + QS;

  dim3 blk(256);

  cvt4_k<<<dim3(CV3 / 256, NLAYER), blk, 0, stream>>>(
      in_proj_w, in_w_bf0, 2 * DINNER * DMODEL / 4,
      pro_w,     pw_bf0,   DINNER * 2 * DINNER / 4,
      token_wA,  wA_bf0,   LSEQ * DINNER / 4,
      out_w,     ow_bf0,   DMODEL * DINNER / 4);
  transcvt_k<<<dim3(1536 / 32, 1536 / 32, NLAYER), blk, 0, stream>>>(
      token_wV, wVT_bf0, 1536, 1536);

  for (int layer = 0; layer < NLAYER; layer++) {
    const float* nw  = norm_w    + (size_t)layer * DMODEL;
    const float* cfw = conv_f_w  + (size_t)layer * DINNER * KCONV;
    const float* cfb = conv_f_b  + (size_t)layer * DINNER;
    const float* cbw = conv_b_w  + (size_t)layer * DINNER * KCONV;
    const float* cbb = conv_b_b  + (size_t)layer * DINNER;
    const float* xfw = xproj_f_w + (size_t)layer * DBC * DINNER;
    const float* xbw = xproj_b_w + (size_t)layer * DBC * DINNER;
    const float* dfw = dt_f_w    + (size_t)layer * DINNER * DRANK;
    const float* dfb = dt_f_b    + (size_t)layer * DINNER;
    const float* dbw = dt_b_w    + (size_t)layer * DINNER * DRANK;
    const float* dbb = dt_b_b    + (size_t)layer * DINNER;
    const float* Af  = A_log_f   + (size_t)layer * DINNER * DSTATE;
    const float* Df  = D_f       + (size_t)layer * DINNER;
    const float* Ab  = A_log_b   + (size_t)layer * DINNER * DSTATE;
    const float* Db  = D_b       + (size_t)layer * DINNER;
    const float* pb  = pro_b     + (size_t)layer * DINNER;

    u16* in_w_bf = in_w_bf0 + (size_t)layer * WBL;
    u16* pw_bf   = pw_bf0   + (size_t)layer * WBL;
    u16* wA_bf   = wA_bf0   + (size_t)layer * WBL;
    u16* wVT_bf  = wVT_bf0  + (size_t)layer * WBL;
    u16* ow_bf   = ow_bf0   + (size_t)layer * WBL;

    const float* xsrc = (layer == 0) ? in_x : xbuf;

    rmsnorm_k<<<LSEQ, blk, 0, stream>>>(xsrc, nw, xn_bf);

    // xz: wide tile, grid 384 (unchanged)
    mgemmW_k<8><<<dim3(3072 / 128, LSEQ / 64), blk, 0, stream>>>(
        xn_bf, DMODEL, in_w_bf, DMODEL, xz_bf, 2 * DINNER, DMODEL, nullptr, nullptr, 0);

    conv_silu_k<<<dim3((LSEQ * DINNER) / 256, 2), blk, 0, stream>>>(
        xz_bf, cfw, cfb, cbw, cbb, xf_bf, xb_bf);

    thin_gemm_k<<<dim3(LSEQ / TG_R, TG_KS, 2), blk, 0, stream>>>(
        xf_bf, xb_bf, xfw, xbw, dbc_part);
    reduce_dbc_k<<<dim3((LSEQ * DBC) / 256, 2), blk, 0, stream>>>(
        dbc_part, dbcf, dbcb);

    delta_gemm_k<<<dim3(DINNER / BN, LSEQ / BM, 2), blk, 0, stream>>>(
        dbcf, dbcb, dfw, dbw, dfb, dbb, delf_bf, delb_bf);

    scan_a_k<<<dim3(DINNER / SCW, NQ - 1, 2), blk, 0, stream>>>(
        xf_bf, xb_bf, delf_bf, delb_bf, dbcf, dbcb, Af, Ab, qsP, qsQ);
    scan_c_k<<<dim3(DINNER / SCW, NQ, 2), blk, 0, stream>>>(
        xf_bf, xb_bf, delf_bf, delb_bf, dbcf, dbcb, Af, Ab, Df, Db, qsP, qsQ, ycat_bf);

    // ypro: back to 64x64 tile -> grid (24,16) = 384 blocks (was 192 wide)
    mgemm_k<9><<<dim3(DINNER / 64, LSEQ / 64), blk, 0, stream>>>(
        ycat_bf, 2 * DINNER, pw_bf, 2 * DINNER, ypro_bf, DINNER, 2 * DINNER,
        pb, nullptr, 0);

    svgemm_k<<<640, blk, 0, stream>>>(wA_bf, ypro_bf, wVT_bf, Smat, vvT_bf);
    softmax_k<<<LSEQ, blk, 0, stream>>>(Smat, Smat_bf);

    // g: back to 64x64 tile -> grid 384 (was 192 wide)
    mgemm_k<56><<<dim3(DINNER / 64, LSEQ / 64), blk, 0, stream>>>(
        Smat_bf, LSEQ, vvT_bf, LSEQ, g_bf, DINNER, LSEQ,
        nullptr, (const float*)(xz_bf + DINNER), 2 * DINNER);

    float* target = (layer == NLAYER - 1) ? (float*)d_out : xbuf;
    mgemm_k<4><<<dim3(DMODEL / 64, LSEQ / 64), blk, 0, stream>>>(
        g_bf, DINNER, ow_bf, DINNER, target, DMODEL, DINNER,
        nullptr, xsrc, DMODEL);
  }
}

// Round 20
// 385.542 us; speedup vs baseline: 1.0785x; 1.0041x over previous
//
#include <hip/hip_runtime.h>
#include <hip/hip_bf16.h>
#include <math.h>
#include <stdint.h>

#define LSEQ 1024
#define DMODEL 768
#define DINNER 1536
#define DSTATE 16
#define DRANK 48
#define KCONV 4
#define NLAYER 2
#define DBC 80  // DRANK + 2*DSTATE
#define NQ 8            // L-split for the 3-phase scan
#define QL (LSEQ / NQ)  // 128
#define SCH 8           // chunks per scan block
#define SCW 32          // channels per scan block (32*2B = full 64B line)
#define QCH (QL / SCH)  // 16 steps per chunk

typedef unsigned short u16;
typedef __attribute__((ext_vector_type(8))) __bf16 bf16x8;
typedef __attribute__((ext_vector_type(4))) float f32x4;
typedef __attribute__((ext_vector_type(4))) unsigned short us4;  // 4 u16 = 8 B

__device__ __forceinline__ u16 f2bf(float f) {
  union { float f; unsigned u; } v; v.f = f;
  unsigned r = v.u + 0x7fffu + ((v.u >> 16) & 1u);  // RNE
  return (u16)(r >> 16);
}
__device__ __forceinline__ float bf2f(u16 u) {
  union { unsigned u; float f; } v; v.u = ((unsigned)u) << 16;
  return v.f;
}

// CK-style addrspace casts for global_load_lds (direct HBM->LDS DMA, 16B/lane)
__device__ __forceinline__ void gload16(const void* g, void* l) {
  auto gp = reinterpret_cast<const __attribute__((address_space(1))) uint32_t*>(
      reinterpret_cast<uintptr_t>(g));
  auto lp = reinterpret_cast<__attribute__((address_space(3))) uint32_t*>(
      reinterpret_cast<uintptr_t>(l));
  __builtin_amdgcn_global_load_lds(gp, lp, 16, 0, 0);
}

// ------------- fused fp32 -> bf16 convert of 4 weight mats, BOTH layers ------
#define CV0 589824              // 3072*768/4
#define CV1 (CV0 + 1179648)     // +1536*3072/4
#define CV2 (CV1 + 393216)      // +1024*1536/4
#define CV3 (CV2 + 294912)      // +768*1536/4 = 2457600 total float4s
#define WBL 12189696            // per-layer bf16 weight region (u16 elems)
__global__ __launch_bounds__(256) void cvt4_k(
    const float* __restrict__ i0, u16* __restrict__ o0, int s0o,
    const float* __restrict__ i1, u16* __restrict__ o1, int s1o,
    const float* __restrict__ i2, u16* __restrict__ o2, int s2o,
    const float* __restrict__ i3, u16* __restrict__ o3, int s3o) {
  int i = blockIdx.x * 256 + threadIdx.x;
  int lay = blockIdx.y;
  const float* in; u16* out; int off;
  if (i < CV0)      { in = i0 + (size_t)lay * s0o * 4; out = o0 + (size_t)lay * WBL; off = i; }
  else if (i < CV1) { in = i1 + (size_t)lay * s1o * 4; out = o1 + (size_t)lay * WBL; off = i - CV0; }
  else if (i < CV2) { in = i2 + (size_t)lay * s2o * 4; out = o2 + (size_t)lay * WBL; off = i - CV1; }
  else              { in = i3 + (size_t)lay * s3o * 4; out = o3 + (size_t)lay * WBL; off = i - CV2; }
  float4 v = ((const float4*)in)[off];
  us4 o; o[0] = f2bf(v.x); o[1] = f2bf(v.y); o[2] = f2bf(v.z); o[3] = f2bf(v.w);
  ((us4*)out)[off] = o;
}

// ---------------- fp32 -> bf16 transpose-convert (both layers via z) ---------
__global__ __launch_bounds__(256) void transcvt_k(const float* __restrict__ in0,
                                                  u16* __restrict__ out0,
                                                  int R, int C) {
  __shared__ float t[32][33];
  const float* in = in0 + (size_t)blockIdx.z * R * C;
  u16* out = out0 + (size_t)blockIdx.z * WBL;
  int c0 = blockIdx.x * 32, r0 = blockIdx.y * 32;
  int tx = threadIdx.x & 31, ty = threadIdx.x >> 5;
  for (int i = ty; i < 32; i += 8) t[i][tx] = in[(size_t)(r0 + i) * C + c0 + tx];
  __syncthreads();
  for (int i = ty; i < 32; i += 8)
    out[(size_t)(c0 + i) * R + r0 + tx] = f2bf(t[tx][i]);
}

// ---------------- rmsnorm (bf16 out) ----------------
__global__ __launch_bounds__(256) void rmsnorm_k(const float* __restrict__ x,
                                                 const float* __restrict__ w,
                                                 u16* __restrict__ xn) {
  int row = blockIdx.x;
  int tid = threadIdx.x;
  const float* xr = x + (size_t)row * DMODEL;
  float ss = 0.f;
  for (int j = tid; j < DMODEL; j += 256) { float v = xr[j]; ss += v * v; }
  __shared__ float red[256];
  red[tid] = ss; __syncthreads();
  for (int s = 128; s > 0; s >>= 1) { if (tid < s) red[tid] += red[tid + s]; __syncthreads(); }
  float scale = rsqrtf(red[0] / (float)DMODEL + 1e-5f);
  u16* outr = xn + (size_t)row * DMODEL;
  for (int j = tid; j < DMODEL; j += 256) outr[j] = f2bf(xr[j] * scale * w[j]);
}

// ---------------- MFMA bf16 GEMM: 64x64 tile -------------
// EPI bit0: +bias; bit2: +resid fp32; bit3: bf16 out; bit4: *silu(resid);
// bit5: resid is bf16.
template<int EPI>
__global__ __launch_bounds__(256) void mgemm_k(
    const u16* __restrict__ A, int lda,
    const u16* __restrict__ B, int ldb,
    void* __restrict__ Cv, int ldc, int K,
    const float* __restrict__ bias,
    const float* __restrict__ resid, int ldr)
{
  __shared__ u16 As[2][64 * 64];
  __shared__ u16 Bs[2][64 * 64];
  const int tid = threadIdx.x;
  const int lane = tid & 63;
  const int w = tid >> 6;

  const int nbx = gridDim.x;
  int bid = blockIdx.y * nbx + blockIdx.x;
  const int nwg = nbx * gridDim.y;
  bid = (bid & 7) * (nwg >> 3) + (bid >> 3);
  const int bm = (bid / nbx) * 64;
  const int bn = (bid % nbx) * 64;

  const int srow = lane >> 3;
  const int scs = (lane & 7) ^ srow;
  const int gA = 2 * w;
  const u16* Asrc0 = A + (size_t)(bm + gA * 8 + srow) * lda + scs * 8;
  const u16* Asrc1 = Asrc0 + (size_t)8 * lda;
  const u16* Bsrc0 = B + (size_t)(bn + gA * 8 + srow) * ldb + scs * 8;
  const u16* Bsrc1 = Bsrc0 + (size_t)8 * ldb;
  const int d0 = gA * 512;
  const int d1 = d0 + 512;

  const int fr = lane & 15;
  const int fs = lane >> 4;
  const int wm = (w >> 1) * 32;
  const int wn = (w & 1) * 32;
  int aoff[2][2], boff[2][2];
#pragma unroll
  for (int i = 0; i < 2; i++)
#pragma unroll
    for (int h = 0; h < 2; h++) {
      const int g = h * 4 + fs;
      aoff[i][h] = (wm + i * 16 + fr) * 64 + (g ^ (fr & 7)) * 8;
      boff[i][h] = (wn + i * 16 + fr) * 64 + (g ^ (fr & 7)) * 8;
    }

  f32x4 acc[2][2];
#pragma unroll
  for (int i = 0; i < 2; i++)
#pragma unroll
    for (int j = 0; j < 2; j++) acc[i][j] = (f32x4){0.f, 0.f, 0.f, 0.f};

#define STAGE(buf, k0) do { \
    gload16(Asrc0 + (k0), &As[buf][d0]); \
    gload16(Asrc1 + (k0), &As[buf][d1]); \
    gload16(Bsrc0 + (k0), &Bs[buf][d0]); \
    gload16(Bsrc1 + (k0), &Bs[buf][d1]); \
  } while (0)

  const int nk = K >> 6;
  STAGE(0, 0);

  for (int t = 0; t < nk; t++) {
    const int buf = t & 1;
    __syncthreads();
    if (t + 1 < nk) STAGE(buf ^ 1, (t + 1) << 6);
    const u16* As_ = As[buf];
    const u16* Bs_ = Bs[buf];
#pragma unroll
    for (int h = 0; h < 2; h++) {
      bf16x8 a0 = *reinterpret_cast<const bf16x8*>(As_ + aoff[0][h]);
      bf16x8 a1 = *reinterpret_cast<const bf16x8*>(As_ + aoff[1][h]);
      bf16x8 b0 = *reinterpret_cast<const bf16x8*>(Bs_ + boff[0][h]);
      bf16x8 b1 = *reinterpret_cast<const bf16x8*>(Bs_ + boff[1][h]);
      acc[0][0] = __builtin_amdgcn_mfma_f32_16x16x32_bf16(a0, b0, acc[0][0], 0, 0, 0);
      acc[0][1] = __builtin_amdgcn_mfma_f32_16x16x32_bf16(a0, b1, acc[0][1], 0, 0, 0);
      acc[1][0] = __builtin_amdgcn_mfma_f32_16x16x32_bf16(a1, b0, acc[1][0], 0, 0, 0);
      acc[1][1] = __builtin_amdgcn_mfma_f32_16x16x32_bf16(a1, b1, acc[1][1], 0, 0, 0);
    }
  }
#undef STAGE

#pragma unroll
  for (int i = 0; i < 2; i++) {
#pragma unroll
    for (int j = 0; j < 2; j++) {
      const int col = bn + wn + j * 16 + fr;
      const int row0 = bm + wm + i * 16 + fs * 4;
      float bv = (EPI & 1) ? bias[col] : 0.f;
#pragma unroll
      for (int r = 0; r < 4; r++) {
        float v = acc[i][j][r] + bv;
        if (EPI & 4) v += resid[(size_t)(row0 + r) * ldr + col];
        if (EPI & 16) {
          float z = (EPI & 32)
              ? bf2f(((const u16*)resid)[(size_t)(row0 + r) * ldr + col])
              : resid[(size_t)(row0 + r) * ldr + col];
          v *= z / (1.f + __expf(-z));
        }
        if (EPI & 8) ((u16*)Cv)[(size_t)(row0 + r) * ldc + col] = f2bf(v);
        else         ((float*)Cv)[(size_t)(row0 + r) * ldc + col] = v;
      }
    }
  }
}

// ------- MFMA bf16 GEMM: 32x64 tile, 4 waves each 16x32 (occupancy variant) --
// grid (N/64, M/32); used for the out GEMM to reach 384 blocks.
template<int EPI>
__global__ __launch_bounds__(256) void mgemmH_k(
    const u16* __restrict__ A, int lda,
    const u16* __restrict__ B, int ldb,
    void* __restrict__ Cv, int ldc, int K,
    const float* __restrict__ bias,
    const float* __restrict__ resid, int ldr)
{
  __shared__ u16 As[2][32 * 64];   // 4 KB per buf
  __shared__ u16 Bs[2][64 * 64];   // 8 KB per buf
  const int tid = threadIdx.x;
  const int lane = tid & 63;
  const int w = tid >> 6;

  const int nbx = gridDim.x;       // N/64
  int bid = blockIdx.y * nbx + blockIdx.x;
  const int nwg = nbx * gridDim.y;
  bid = (bid & 7) * (nwg >> 3) + (bid >> 3);
  const int bm = (bid / nbx) * 32;
  const int bn = (bid % nbx) * 64;

  const int srow = lane >> 3;
  const int scs = (lane & 7) ^ srow;
  // A tile: 32 rows = 4 gloads; wave w stages rows [8w, 8w+8)
  const u16* Asrc = A + (size_t)(bm + w * 8 + srow) * lda + scs * 8;
  const int dA = w * 512;
  // B tile: 64 rows = 8 gloads; wave w stages rows [16w, 16w+8), [16w+8, 16w+16)
  const u16* Bsrc0 = B + (size_t)(bn + w * 16 + srow) * ldb + scs * 8;
  const u16* Bsrc1 = Bsrc0 + (size_t)8 * ldb;
  const int dB0 = (2 * w) * 512;
  const int dB1 = dB0 + 512;

  const int fr = lane & 15;
  const int fs = lane >> 4;
  const int wm = (w >> 1) * 16;    // 0 / 16
  const int wn = (w & 1) * 32;     // 0 / 32
  int aoff[2], boff[2][2];
#pragma unroll
  for (int h = 0; h < 2; h++) {
    const int g = h * 4 + fs;
    const int sw = (g ^ (fr & 7)) * 8;
    aoff[h] = (wm + fr) * 64 + sw;
#pragma unroll
    for (int j = 0; j < 2; j++) boff[j][h] = (wn + j * 16 + fr) * 64 + sw;
  }

  f32x4 acc[2];
  acc[0] = (f32x4){0.f, 0.f, 0.f, 0.f};
  acc[1] = (f32x4){0.f, 0.f, 0.f, 0.f};

#define STAGEH(buf, k0) do { \
    gload16(Asrc + (k0), &As[buf][dA]); \
    gload16(Bsrc0 + (k0), &Bs[buf][dB0]); \
    gload16(Bsrc1 + (k0), &Bs[buf][dB1]); \
  } while (0)

  const int nk = K >> 6;
  STAGEH(0, 0);

  for (int t = 0; t < nk; t++) {
    const int buf = t & 1;
    __syncthreads();
    if (t + 1 < nk) STAGEH(buf ^ 1, (t + 1) << 6);
    const u16* As_ = As[buf];
    const u16* Bs_ = Bs[buf];
#pragma unroll
    for (int h = 0; h < 2; h++) {
      bf16x8 a = *reinterpret_cast<const bf16x8*>(As_ + aoff[h]);
      bf16x8 b0 = *reinterpret_cast<const bf16x8*>(Bs_ + boff[0][h]);
      bf16x8 b1 = *reinterpret_cast<const bf16x8*>(Bs_ + boff[1][h]);
      acc[0] = __builtin_amdgcn_mfma_f32_16x16x32_bf16(a, b0, acc[0], 0, 0, 0);
      acc[1] = __builtin_amdgcn_mfma_f32_16x16x32_bf16(a, b1, acc[1], 0, 0, 0);
    }
  }
#undef STAGEH

#pragma unroll
  for (int j = 0; j < 2; j++) {
    const int col = bn + wn + j * 16 + fr;
    const int row0 = bm + wm + fs * 4;
    float bv = (EPI & 1) ? bias[col] : 0.f;
#pragma unroll
    for (int r = 0; r < 4; r++) {
      float v = acc[j][r] + bv;
      if (EPI & 4) v += resid[(size_t)(row0 + r) * ldr + col];
      if (EPI & 16) {
        float z = (EPI & 32)
            ? bf2f(((const u16*)resid)[(size_t)(row0 + r) * ldr + col])
            : resid[(size_t)(row0 + r) * ldr + col];
        v *= z / (1.f + __expf(-z));
      }
      if (EPI & 8) ((u16*)Cv)[(size_t)(row0 + r) * ldc + col] = f2bf(v);
      else         ((float*)Cv)[(size_t)(row0 + r) * ldc + col] = v;
    }
  }
}

// ------- MFMA bf16 GEMM: 64x128 tile (xz only; grid stays >= 384) ------------
template<int EPI>
__global__ __launch_bounds__(256) void mgemmW_k(
    const u16* __restrict__ A, int lda,
    const u16* __restrict__ B, int ldb,
    void* __restrict__ Cv, int ldc, int K,
    const float* __restrict__ bias,
    const float* __restrict__ resid, int ldr)
{
  __shared__ u16 As[2][64 * 64];
  __shared__ u16 Bs[2][128 * 64];
  const int tid = threadIdx.x;
  const int lane = tid & 63;
  const int w = tid >> 6;

  const int nbx = gridDim.x;
  int bid = blockIdx.y * nbx + blockIdx.x;
  const int nwg = nbx * gridDim.y;
  bid = (bid & 7) * (nwg >> 3) + (bid >> 3);
  const int bm = (bid / nbx) * 64;
  const int bn = (bid % nbx) * 128;

  const int srow = lane >> 3;
  const int scs = (lane & 7) ^ srow;
  const u16* Asrc0 = A + (size_t)(bm + (2 * w) * 8 + srow) * lda + scs * 8;
  const u16* Asrc1 = Asrc0 + (size_t)8 * lda;
  const int da0 = (2 * w) * 512, da1 = da0 + 512;
  const u16* Bsrc0 = B + (size_t)(bn + (4 * w) * 8 + srow) * ldb + scs * 8;
  const u16* Bsrc1 = Bsrc0 + (size_t)8 * ldb;
  const u16* Bsrc2 = Bsrc1 + (size_t)8 * ldb;
  const u16* Bsrc3 = Bsrc2 + (size_t)8 * ldb;
  const int db0 = (4 * w) * 512;

  const int fr = lane & 15;
  const int fs = lane >> 4;
  const int wm = (w >> 1) * 32;
  const int wn = (w & 1) * 64;
  int aoff[2][2], boff[4][2];
#pragma unroll
  for (int h = 0; h < 2; h++) {
    const int g = h * 4 + fs;
    const int sw = (g ^ (fr & 7)) * 8;
#pragma unroll
    for (int i = 0; i < 2; i++) aoff[i][h] = (wm + i * 16 + fr) * 64 + sw;
#pragma unroll
    for (int j = 0; j < 4; j++) boff[j][h] = (wn + j * 16 + fr) * 64 + sw;
  }

  f32x4 acc[2][4];
#pragma unroll
  for (int i = 0; i < 2; i++)
#pragma unroll
    for (int j = 0; j < 4; j++) acc[i][j] = (f32x4){0.f, 0.f, 0.f, 0.f};

#define STAGEW(buf, k0) do { \
    gload16(Asrc0 + (k0), &As[buf][da0]); \
    gload16(Asrc1 + (k0), &As[buf][da1]); \
    gload16(Bsrc0 + (k0), &Bs[buf][db0]); \
    gload16(Bsrc1 + (k0), &Bs[buf][db0 + 512]); \
    gload16(Bsrc2 + (k0), &Bs[buf][db0 + 1024]); \
    gload16(Bsrc3 + (k0), &Bs[buf][db0 + 1536]); \
  } while (0)

  const int nk = K >> 6;
  STAGEW(0, 0);

  for (int t = 0; t < nk; t++) {
    const int buf = t & 1;
    __syncthreads();
    if (t + 1 < nk) STAGEW(buf ^ 1, (t + 1) << 6);
    const u16* As_ = As[buf];
    const u16* Bs_ = Bs[buf];
#pragma unroll
    for (int h = 0; h < 2; h++) {
      bf16x8 a0 = *reinterpret_cast<const bf16x8*>(As_ + aoff[0][h]);
      bf16x8 a1 = *reinterpret_cast<const bf16x8*>(As_ + aoff[1][h]);
#pragma unroll
      for (int j = 0; j < 4; j++) {
        bf16x8 b = *reinterpret_cast<const bf16x8*>(Bs_ + boff[j][h]);
        acc[0][j] = __builtin_amdgcn_mfma_f32_16x16x32_bf16(a0, b, acc[0][j], 0, 0, 0);
        acc[1][j] = __builtin_amdgcn_mfma_f32_16x16x32_bf16(a1, b, acc[1][j], 0, 0, 0);
      }
    }
  }
#undef STAGEW

#pragma unroll
  for (int i = 0; i < 2; i++) {
#pragma unroll
    for (int j = 0; j < 4; j++) {
      const int col = bn + wn + j * 16 + fr;
      const int row0 = bm + wm + i * 16 + fs * 4;
      float bv = (EPI & 1) ? bias[col] : 0.f;
#pragma unroll
      for (int r = 0; r < 4; r++) {
        float v = acc[i][j][r] + bv;
        if (EPI & 4) v += resid[(size_t)(row0 + r) * ldr + col];
        if (EPI & 16) {
          float z = (EPI & 32)
              ? bf2f(((const u16*)resid)[(size_t)(row0 + r) * ldr + col])
              : resid[(size_t)(row0 + r) * ldr + col];
          v *= z / (1.f + __expf(-z));
        }
        if (EPI & 8) ((u16*)Cv)[(size_t)(row0 + r) * ldc + col] = f2bf(v);
        else         ((float*)Cv)[(size_t)(row0 + r) * ldc + col] = v;
      }
    }
  }
}

// ---------------- fused S + vv GEMM; vv part writes vvT directly -------------
__global__ __launch_bounds__(256) void svgemm_k(
    const u16* __restrict__ wA, const u16* __restrict__ ypro,
    const u16* __restrict__ wVT,
    float* __restrict__ Smat, u16* __restrict__ vvT)
{
  __shared__ u16 As[2][64 * 64];
  __shared__ u16 Bs[2][64 * 64];
  __shared__ u16 tr[4][32][33];
  const int tid = threadIdx.x;
  const int lane = tid & 63;
  const int w = tid >> 6;

  int bid = blockIdx.x;
  bid = (bid & 7) * 80 + (bid >> 3);
  const bool is_s = bid < 256;
  const u16* A;
  const u16* B;
  int bm, bn;
  if (is_s) { A = wA;   B = ypro; bm = (bid >> 4) * 64;         bn = (bid & 15) * 64; }
  else      { A = ypro; B = wVT;  bm = ((bid - 256) / 24) * 64; bn = ((bid - 256) % 24) * 64; }

  const int srow = lane >> 3;
  const int scs = (lane & 7) ^ srow;
  const int gA = 2 * w;
  const u16* Asrc0 = A + (size_t)(bm + gA * 8 + srow) * DINNER + scs * 8;
  const u16* Asrc1 = Asrc0 + (size_t)8 * DINNER;
  const u16* Bsrc0 = B + (size_t)(bn + gA * 8 + srow) * DINNER + scs * 8;
  const u16* Bsrc1 = Bsrc0 + (size_t)8 * DINNER;
  const int d0 = gA * 512;
  const int d1 = d0 + 512;

  const int fr = lane & 15;
  const int fs = lane >> 4;
  const int wm = (w >> 1) * 32;
  const int wn = (w & 1) * 32;
  int aoff[2][2], boff[2][2];
#pragma unroll
  for (int i = 0; i < 2; i++)
#pragma unroll
    for (int h = 0; h < 2; h++) {
      const int g = h * 4 + fs;
      aoff[i][h] = (wm + i * 16 + fr) * 64 + (g ^ (fr & 7)) * 8;
      boff[i][h] = (wn + i * 16 + fr) * 64 + (g ^ (fr & 7)) * 8;
    }

  f32x4 acc[2][2];
#pragma unroll
  for (int i = 0; i < 2; i++)
#pragma unroll
    for (int j = 0; j < 2; j++) acc[i][j] = (f32x4){0.f, 0.f, 0.f, 0.f};

#define STAGE(buf, k0) do { \
    gload16(Asrc0 + (k0), &As[buf][d0]); \
    gload16(Asrc1 + (k0), &As[buf][d1]); \
    gload16(Bsrc0 + (k0), &Bs[buf][d0]); \
    gload16(Bsrc1 + (k0), &Bs[buf][d1]); \
  } while (0)

  STAGE(0, 0);
  for (int t = 0; t < DINNER / 64; t++) {
    const int buf = t & 1;
    __syncthreads();
    if (t + 1 < DINNER / 64) STAGE(buf ^ 1, (t + 1) << 6);
    const u16* As_ = As[buf];
    const u16* Bs_ = Bs[buf];
#pragma unroll
    for (int h = 0; h < 2; h++) {
      bf16x8 a0 = *reinterpret_cast<const bf16x8*>(As_ + aoff[0][h]);
      bf16x8 a1 = *reinterpret_cast<const bf16x8*>(As_ + aoff[1][h]);
      bf16x8 b0 = *reinterpret_cast<const bf16x8*>(Bs_ + boff[0][h]);
      bf16x8 b1 = *reinterpret_cast<const bf16x8*>(Bs_ + boff[1][h]);
      acc[0][0] = __builtin_amdgcn_mfma_f32_16x16x32_bf16(a0, b0, acc[0][0], 0, 0, 0);
      acc[0][1] = __builtin_amdgcn_mfma_f32_16x16x32_bf16(a0, b1, acc[0][1], 0, 0, 0);
      acc[1][0] = __builtin_amdgcn_mfma_f32_16x16x32_bf16(a1, b0, acc[1][0], 0, 0, 0);
      acc[1][1] = __builtin_amdgcn_mfma_f32_16x16x32_bf16(a1, b1, acc[1][1], 0, 0, 0);
    }
  }
#undef STAGE

  if (is_s) {
#pragma unroll
    for (int i = 0; i < 2; i++)
#pragma unroll
      for (int j = 0; j < 2; j++) {
        const int col = bn + wn + j * 16 + fr;
        const int row0 = bm + wm + i * 16 + fs * 4;
#pragma unroll
        for (int r = 0; r < 4; r++)
          Smat[(size_t)(row0 + r) * LSEQ + col] = acc[i][j][r];
      }
  } else {
#pragma unroll
    for (int i = 0; i < 2; i++)
#pragma unroll
      for (int j = 0; j < 2; j++) {
        const int lr0 = i * 16 + fs * 4;
        const int lc = j * 16 + fr;
#pragma unroll
        for (int r = 0; r < 4; r++) tr[w][lr0 + r][lc] = f2bf(acc[i][j][r]);
      }
    __syncthreads();
    const int lc = lane >> 1;
    const int half = lane & 1;
    const int gcol = bn + wn + lc;
    const int grow0 = bm + wm + half * 16;
    u16* dst = vvT + (size_t)gcol * LSEQ + grow0;
#pragma unroll
    for (int q = 0; q < 4; q++) {
      us4 v;
#pragma unroll
      for (int e = 0; e < 4; e++) v[e] = tr[w][half * 16 + q * 4 + e][lc];
      *(us4*)(dst + q * 4) = v;
    }
  }
}

// ---------------- thin dbc GEMM (bf16 A, f+b merged) -------------------------
#define TG_R 16
#define TG_KC 96
#define TG_KS 16

__global__ __launch_bounds__(256) void thin_gemm_k(
    const u16* __restrict__ Af_, const u16* __restrict__ Ab_,
    const float* __restrict__ Bf_, const float* __restrict__ Bb_,
    float* __restrict__ partial)
{
  __shared__ u16 As[TG_R][TG_KC];
  __shared__ float Bs[80][100];
  const u16* A = blockIdx.z ? Ab_ : Af_;
  const float* B = blockIdx.z ? Bb_ : Bf_;
  float* part = partial + (size_t)blockIdx.z * TG_KS * LSEQ * DBC;
  const int tid = threadIdx.x;
  const int m0 = blockIdx.x * TG_R;
  const int ks = blockIdx.y;
  const int k0 = ks * TG_KC;

  for (int i = tid; i < 384; i += 256) {
    int r = i / 24, q = i % 24;
    *(us4*)&As[r][q * 4] = *(const us4*)(A + (size_t)(m0 + r) * DINNER + k0 + q * 4);
  }
  for (int i = tid; i < 1920; i += 256) {
    int r = i / 24, q = i % 24;
    *(float4*)&Bs[r][q * 4] = *(const float4*)(B + (size_t)r * DINNER + k0 + q * 4);
  }
  __syncthreads();

  const int r = tid >> 4;
  const int c0 = (tid & 15) * 5;
  float acc[5] = {};
  for (int k = 0; k < TG_KC; k++) {
    float a = bf2f(As[r][k]);
#pragma unroll
    for (int j = 0; j < 5; j++) acc[j] += a * Bs[c0 + j][k];
  }
  float* out = part + ((size_t)ks * LSEQ + m0 + r) * DBC + c0;
#pragma unroll
  for (int j = 0; j < 5; j++) out[j] = acc[j];
}

__global__ __launch_bounds__(256) void reduce_dbc_k(const float* __restrict__ partial,
                                                    float* __restrict__ outf,
                                                    float* __restrict__ outb) {
  int i = blockIdx.x * 256 + threadIdx.x;
  const float* part = partial + (size_t)blockIdx.y * TG_KS * LSEQ * DBC;
  float s = 0.f;
#pragma unroll
  for (int ks = 0; ks < TG_KS; ks++) s += part[(size_t)ks * (LSEQ * DBC) + i];
  (blockIdx.y ? outb : outf)[i] = s;
}

// ---------------- delta = softplus(dlt @ dt_w^T + dt_b), f+b merged, bf16 out
#define BM 64
#define BN 64
#define BK 16

__global__ __launch_bounds__(256) void delta_gemm_k(
    const float* __restrict__ A0, const float* __restrict__ A1,
    const float* __restrict__ B0, const float* __restrict__ B1,
    const float* __restrict__ b0, const float* __restrict__ b1,
    u16* __restrict__ C0, u16* __restrict__ C1)
{
  __shared__ float Asf[BK][BM];
  __shared__ float Bsf[BK][BN + 4];
  const float* A = blockIdx.z ? A1 : A0;
  const float* B = blockIdx.z ? B1 : B0;
  const float* bias = blockIdx.z ? b1 : b0;
  u16* C = blockIdx.z ? C1 : C0;
  const int tid = threadIdx.x;
  const int bm = blockIdx.y * BM;
  const int bn = blockIdx.x * BN;
  const int ar = tid >> 2;
  const int ak = (tid & 3) << 2;
  const int ty = tid >> 4, tx = tid & 15;
  float acc[4][4] = {};

  for (int k0 = 0; k0 < DRANK; k0 += BK) {
    float4 av = *(const float4*)(A + (size_t)(bm + ar) * DBC + k0 + ak);
    float4 bv = *(const float4*)(B + (size_t)(bn + ar) * DRANK + k0 + ak);
    __syncthreads();
    Asf[ak + 0][ar] = av.x; Asf[ak + 1][ar] = av.y;
    Asf[ak + 2][ar] = av.z; Asf[ak + 3][ar] = av.w;
    Bsf[ak + 0][ar] = bv.x; Bsf[ak + 1][ar] = bv.y;
    Bsf[ak + 2][ar] = bv.z; Bsf[ak + 3][ar] = bv.w;
    __syncthreads();
#pragma unroll
    for (int kk = 0; kk < BK; kk++) {
      float4 a4 = *(const float4*)&Asf[kk][ty * 4];
      float4 b4 = *(const float4*)&Bsf[kk][tx * 4];
      float a[4] = {a4.x, a4.y, a4.z, a4.w};
      float b[4] = {b4.x, b4.y, b4.z, b4.w};
#pragma unroll
      for (int i = 0; i < 4; i++)
#pragma unroll
        for (int j = 0; j < 4; j++)
          acc[i][j] += a[i] * b[j];
    }
  }

#pragma unroll
  for (int i = 0; i < 4; i++) {
    int row = bm + ty * 4 + i;
#pragma unroll
    for (int j = 0; j < 4; j++) {
      int col = bn + tx * 4 + j;
      float v = acc[i][j] + bias[col];
      v = (v > 20.f) ? v : log1pf(__expf(v));
      C[(size_t)row * DINNER + col] = f2bf(v);
    }
  }
}

// ---------------- causal depthwise conv + silu (bf16 in/out, both dirs) ------
__global__ __launch_bounds__(256) void conv_silu_k(
    const u16* __restrict__ xz,
    const float* __restrict__ wf, const float* __restrict__ bf,
    const float* __restrict__ wb, const float* __restrict__ bb,
    u16* __restrict__ xf, u16* __restrict__ xb)
{
  int idx = blockIdx.x * 256 + threadIdx.x;
  int dir = blockIdx.y;
  if (idx >= LSEQ * DINNER) return;
  int l = idx / DINNER, c = idx % DINNER;
  const float* w = (dir ? wb : wf) + c * KCONV;
  float acc = (dir ? bb : bf)[c];
#pragma unroll
  for (int k = 0; k < KCONV; k++) {
    int ls = l - (KCONV - 1) + k;
    if (ls >= 0) {
      int lsrc = dir ? (LSEQ - 1 - ls) : ls;
      acc += w[k] * bf2f(xz[(size_t)lsrc * (2 * DINNER) + c]);
    }
  }
  float sv = acc / (1.f + __expf(-acc));
  (dir ? xb : xf)[idx] = f2bf(sv);
}

// ---------------- 3-phase L-split scan (fast-exp) ----------------------------
// FAST-EXP: A_log = log(1..16) in this model, so Aa[s] = Aa0*(s+1) and
// exp(dt*Aa[s]) = exp(dt*Aa0)^(s+1) — 1 exp + 15 muls instead of 16 exps.
// Verified per-thread with rel tol 1e-4; generic exp fallback otherwise.
__global__ __launch_bounds__(256) void scan_a_k(
    const u16* __restrict__ xcf, const u16* __restrict__ xcb,
    const u16* __restrict__ dltf, const u16* __restrict__ dltb,
    const float* __restrict__ dbcf, const float* __restrict__ dbcb,
    const float* __restrict__ Af, const float* __restrict__ Ab,
    float* __restrict__ qsP, float* __restrict__ qsQ)
{
  __shared__ float sP[SCH * SCW * DSTATE];
  __shared__ float sQ[SCH * SCW * DSTATE];
  const int dir = blockIdx.z;
  const int qid = blockIdx.y;   // 0..NQ-2 (last octave's summary never used)
  const u16*   xc    = dir ? xcb : xcf;
  const u16*   delta = dir ? dltb : dltf;
  const float* dbc   = dir ? dbcb : dbcf;
  const float* A_log = dir ? Ab : Af;

  const int tid = threadIdx.x;
  const int c = tid >> 5;
  const int dl = tid & 31;
  const int d = blockIdx.x * SCW + dl;

  float Aa[DSTATE];
#pragma unroll
  for (int s = 0; s < DSTATE; s++) Aa[s] = -__expf(A_log[(size_t)d * DSTATE + s]);
  const float Aa0 = Aa[0];
  bool fast = true;
#pragma unroll
  for (int s = 1; s < DSTATE; s++)
    fast = fast && (fabsf(Aa[s] - Aa0 * (float)(s + 1)) <= 1e-4f * fabsf(Aa[s]));

  float aP[DSTATE], q[DSTATE];
#pragma unroll
  for (int s = 0; s < DSTATE; s++) { aP[s] = 1.f; q[s] = 0.f; }
  const int l0 = qid * QL + c * QCH;
  if (fast) {
    for (int i = 0; i < QCH; i++) {
      int l = l0 + i;
      float dt = bf2f(delta[(size_t)l * DINNER + d]);
      float dx = dt * bf2f(xc[(size_t)l * DINNER + d]);
      const float* bm = dbc + (size_t)l * DBC + DRANK;
      float e0 = __expf(dt * Aa0);
      float a = 1.f;
#pragma unroll
      for (int s = 0; s < DSTATE; s++) {
        a *= e0;
        q[s] = a * q[s] + dx * bm[s];
        aP[s] *= a;
      }
    }
  } else {
    for (int i = 0; i < QCH; i++) {
      int l = l0 + i;
      float dt = bf2f(delta[(size_t)l * DINNER + d]);
      float dx = dt * bf2f(xc[(size_t)l * DINNER + d]);
      const float* bm = dbc + (size_t)l * DBC + DRANK;
#pragma unroll
      for (int s = 0; s < DSTATE; s++) {
        float a = __expf(dt * Aa[s]);
        q[s] = a * q[s] + dx * bm[s];
        aP[s] *= a;
      }
    }
  }
#pragma unroll
  for (int s = 0; s < DSTATE; s++) {
    sP[(c * SCW + dl) * DSTATE + s] = aP[s];
    sQ[(c * SCW + dl) * DSTATE + s] = q[s];
  }
  __syncthreads();

#pragma unroll
  for (int pp = 0; pp < 2; pp++) {
    const int p = tid + pp * 256;
    const int d2 = p >> 4, s2 = p & 15;
    float h = 0.f, P = 1.f;
    for (int cc = 0; cc < SCH; cc++) {
      int idx = (cc * SCW + d2) * DSTATE + s2;
      h = sP[idx] * h + sQ[idx];
      P *= sP[idx];
    }
    size_t o = (((size_t)dir * NQ + qid) * DINNER + blockIdx.x * SCW + d2) * DSTATE + s2;
    qsP[o] = P;
    qsQ[o] = h;
  }
}

__global__ __launch_bounds__(256) void scan_c_k(
    const u16* __restrict__ xcf, const u16* __restrict__ xcb,
    const u16* __restrict__ dltf, const u16* __restrict__ dltb,
    const float* __restrict__ dbcf, const float* __restrict__ dbcb,
    const float* __restrict__ Af, const float* __restrict__ Ab,
    const float* __restrict__ Df, const float* __restrict__ Db,
    const float* __restrict__ qsP, const float* __restrict__ qsQ,
    u16* __restrict__ ycat)
{
  __shared__ float sP[SCH * SCW * DSTATE];
  __shared__ float sQ[SCH * SCW * DSTATE];
  const int dir = blockIdx.z;
  const int qid = blockIdx.y;
  const u16*   xc    = dir ? xcb : xcf;
  const u16*   delta = dir ? dltb : dltf;
  const float* dbc   = dir ? dbcb : dbcf;
  const float* A_log = dir ? Ab : Af;
  const float* Dvec  = dir ? Db : Df;
  const int col_off  = dir ? DINNER : 0;

  const int tid = threadIdx.x;
  const int c = tid >> 5;
  const int dl = tid & 31;
  const int d = blockIdx.x * SCW + dl;

  float Aa[DSTATE];
#pragma unroll
  for (int s = 0; s < DSTATE; s++) Aa[s] = -__expf(A_log[(size_t)d * DSTATE + s]);
  const float Aa0 = Aa[0];
  bool fast = true;
#pragma unroll
  for (int s = 1; s < DSTATE; s++)
    fast = fast && (fabsf(Aa[s] - Aa0 * (float)(s + 1)) <= 1e-4f * fabsf(Aa[s]));

  float aP[DSTATE], q[DSTATE];
#pragma unroll
  for (int s = 0; s < DSTATE; s++) { aP[s] = 1.f; q[s] = 0.f; }
  const int l0 = qid * QL + c * QCH;
  if (fast) {
    for (int i = 0; i < QCH; i++) {
      int l = l0 + i;
      float dt = bf2f(delta[(size_t)l * DINNER + d]);
      float dx = dt * bf2f(xc[(size_t)l * DINNER + d]);
      const float* bm = dbc + (size_t)l * DBC + DRANK;
      float e0 = __expf(dt * Aa0);
      float a = 1.f;
#pragma unroll
      for (int s = 0; s < DSTATE; s++) {
        a *= e0;
        q[s] = a * q[s] + dx * bm[s];
        aP[s] *= a;
      }
    }
  } else {
    for (int i = 0; i < QCH; i++) {
      int l = l0 + i;
      float dt = bf2f(delta[(size_t)l * DINNER + d]);
      float dx = dt * bf2f(xc[(size_t)l * DINNER + d]);
      const float* bm = dbc + (size_t)l * DBC + DRANK;
#pragma unroll
      for (int s = 0; s < DSTATE; s++) {
        float a = __expf(dt * Aa[s]);
        q[s] = a * q[s] + dx * bm[s];
        aP[s] *= a;
      }
    }
  }
#pragma unroll
  for (int s = 0; s < DSTATE; s++) {
    sP[(c * SCW + dl) * DSTATE + s] = aP[s];
    sQ[(c * SCW + dl) * DSTATE + s] = q[s];
  }
  __syncthreads();

#pragma unroll
  for (int pp = 0; pp < 2; pp++) {
    const int p = tid + pp * 256;
    const int d2 = p >> 4, s2 = p & 15;
    float h = 0.f;
    for (int qq = 0; qq < qid; qq++) {
      size_t o = (((size_t)dir * NQ + qq) * DINNER + blockIdx.x * SCW + d2) * DSTATE + s2;
      h = qsP[o] * h + qsQ[o];
    }
    for (int cc = 0; cc < SCH; cc++) {
      int idx = (cc * SCW + d2) * DSTATE + s2;
      float a = sP[idx], qv = sQ[idx];
      sP[idx] = h;
      h = a * h + qv;
    }
  }
  __syncthreads();

  float hs[DSTATE];
#pragma unroll
  for (int s = 0; s < DSTATE; s++) hs[s] = sP[(c * SCW + dl) * DSTATE + s];
  const float Dd = Dvec[d];
  if (fast) {
    for (int i = 0; i < QCH; i++) {
      int l = l0 + i;
      float dt = bf2f(delta[(size_t)l * DINNER + d]);
      float xv = bf2f(xc[(size_t)l * DINNER + d]);
      float dx = dt * xv;
      const float* bm = dbc + (size_t)l * DBC + DRANK;
      const float* cm = bm + DSTATE;
      float e0 = __expf(dt * Aa0);
      float a = 1.f;
      float y = 0.f;
#pragma unroll
      for (int s = 0; s < DSTATE; s++) {
        a *= e0;
        hs[s] = a * hs[s] + dx * bm[s];
        y += hs[s] * cm[s];
      }
      ycat[(size_t)l * (2 * DINNER) + col_off + d] = f2bf(y + Dd * xv);
    }
  } else {
    for (int i = 0; i < QCH; i++) {
      int l = l0 + i;
      float dt = bf2f(delta[(size_t)l * DINNER + d]);
      float xv = bf2f(xc[(size_t)l * DINNER + d]);
      float dx = dt * xv;
      const float* bm = dbc + (size_t)l * DBC + DRANK;
      const float* cm = bm + DSTATE;
      float y = 0.f;
#pragma unroll
      for (int s = 0; s < DSTATE; s++) {
        float a = __expf(dt * Aa[s]);
        hs[s] = a * hs[s] + dx * bm[s];
        y += hs[s] * cm[s];
      }
      ycat[(size_t)l * (2 * DINNER) + col_off + d] = f2bf(y + Dd * xv);
    }
  }
}

// ---------------- row softmax (fp32 in, bf16 out) ----------------
__global__ __launch_bounds__(256) void softmax_k(const float* __restrict__ S,
                                                 u16* __restrict__ P) {
  int row = blockIdx.x, tid = threadIdx.x;
  __shared__ float buf[LSEQ];
  __shared__ float red[256];
  const float* r = S + (size_t)row * LSEQ;
  float m = -1e30f;
  for (int j = tid; j < LSEQ; j += 256) { float v = r[j]; buf[j] = v; m = fmaxf(m, v); }
  red[tid] = m; __syncthreads();
  for (int s = 128; s > 0; s >>= 1) { if (tid < s) red[tid] = fmaxf(red[tid], red[tid + s]); __syncthreads(); }
  m = red[0];
  __syncthreads();
  float sum = 0.f;
  for (int j = tid; j < LSEQ; j += 256) { float e = __expf(buf[j] - m); buf[j] = e; sum += e; }
  red[tid] = sum; __syncthreads();
  for (int s = 128; s > 0; s >>= 1) { if (tid < s) red[tid] += red[tid + s]; __syncthreads(); }
  float inv = 1.f / red[0];
  u16* pr = P + (size_t)row * LSEQ;
  for (int j = tid; j < LSEQ; j += 256) pr[j] = f2bf(buf[j] * inv);
}

extern "C" void kernel_launch(void* const* d_in, const int* in_sizes, int n_in,
                              void* d_out, int out_size, void* d_ws, size_t ws_size,
                              hipStream_t stream) {
  const float* in_x      = (const float*)d_in[0];
  const float* norm_w    = (const float*)d_in[1];
  const float* in_proj_w = (const float*)d_in[2];
  const float* conv_f_w  = (const float*)d_in[3];
  const float* conv_f_b  = (const float*)d_in[4];
  const float* conv_b_w  = (const float*)d_in[5];
  const float* conv_b_b  = (const float*)d_in[6];
  const float* xproj_f_w = (const float*)d_in[7];
  const float* xproj_b_w = (const float*)d_in[8];
  const float* dt_f_w    = (const float*)d_in[9];
  const float* dt_f_b    = (const float*)d_in[10];
  const float* dt_b_w    = (const float*)d_in[11];
  const float* dt_b_b    = (const float*)d_in[12];
  const float* A_log_f   = (const float*)d_in[13];
  const float* D_f       = (const float*)d_in[14];
  const float* A_log_b   = (const float*)d_in[15];
  const float* D_b       = (const float*)d_in[16];
  const float* out_w     = (const float*)d_in[17];
  const float* token_wA  = (const float*)d_in[18];
  const float* token_wV  = (const float*)d_in[19];
  const float* pro_w     = (const float*)d_in[20];
  const float* pro_b     = (const float*)d_in[21];

  // ---- workspace carve (fp32 units) ----
  float* ws = (float*)d_ws;
  float* xbuf = ws; ws += LSEQ * DMODEL;
  u16* xz_bf  = (u16*)ws; ws += LSEQ * DINNER;
  u16* xf_bf  = (u16*)ws; ws += (LSEQ * DINNER) / 2;
  u16* xb_bf  = (u16*)ws; ws += (LSEQ * DINNER) / 2;
  float* dbcf = ws; ws += LSEQ * DBC;
  float* dbcb = ws; ws += LSEQ * DBC;
  float* delf_r = ws; ws += LSEQ * DINNER;
  float* delb_r = ws; ws += LSEQ * DINNER;
  float* scr  = ws; ws += LSEQ * DINNER;
  u16* xn_bf   = (u16*)ws; ws += (LSEQ * DMODEL) / 2;
  u16* ycat_bf = (u16*)ws; ws += LSEQ * DINNER;
  u16* ypro_bf = (u16*)ws; ws += (LSEQ * DINNER) / 2;
  u16* Wb      = (u16*)ws;

  u16* in_w_bf0 = Wb;
  u16* pw_bf0   = in_w_bf0 + 3072 * 768;
  u16* wA_bf0   = pw_bf0 + 1536 * 3072;
  u16* wVT_bf0  = wA_bf0 + 1024 * 1536;
  u16* ow_bf0   = wVT_bf0 + 1536 * 1536;

  float* dbc_part = delf_r;
  u16*   delf_bf  = (u16*)delf_r;
  u16*   delb_bf  = (u16*)delb_r;
  float* Smat     = delf_r;
  u16*   Smat_bf  = (u16*)delb_r;
  u16*   vvT_bf   = xb_bf;        // xb dead after scan_c
  u16*   g_bf     = ypro_bf;
  const int QS = 2 * NQ * DINNER * DSTATE;
  float* qsP   = scr;
  float* qsQ   = scr + QS;

  dim3 blk(256);

  cvt4_k<<<dim3(CV3 / 256, NLAYER), blk, 0, stream>>>(
      in_proj_w, in_w_bf0, 2 * DINNER * DMODEL / 4,
      pro_w,     pw_bf0,   DINNER * 2 * DINNER / 4,
      token_wA,  wA_bf0,   LSEQ * DINNER / 4,
      out_w,     ow_bf0,   DMODEL * DINNER / 4);
  transcvt_k<<<dim3(1536 / 32, 1536 / 32, NLAYER), blk, 0, stream>>>(
      token_wV, wVT_bf0, 1536, 1536);

  for (int layer = 0; layer < NLAYER; layer++) {
    const float* nw  = norm_w    + (size_t)layer * DMODEL;
    const float* cfw = conv_f_w  + (size_t)layer * DINNER * KCONV;
    const float* cfb = conv_f_b  + (size_t)layer * DINNER;
    const float* cbw = conv_b_w  + (size_t)layer * DINNER * KCONV;
    const float* cbb = conv_b_b  + (size_t)layer * DINNER;
    const float* xfw = xproj_f_w + (size_t)layer * DBC * DINNER;
    const float* xbw = xproj_b_w + (size_t)layer * DBC * DINNER;
    const float* dfw = dt_f_w    + (size_t)layer * DINNER * DRANK;
    const float* dfb = dt_f_b    + (size_t)layer * DINNER;
    const float* dbw = dt_b_w    + (size_t)layer * DINNER * DRANK;
    const float* dbb = dt_b_b    + (size_t)layer * DINNER;
    const float* Af  = A_log_f   + (size_t)layer * DINNER * DSTATE;
    const float* Df  = D_f       + (size_t)layer * DINNER;
    const float* Ab  = A_log_b   + (size_t)layer * DINNER * DSTATE;
    const float* Db  = D_b       + (size_t)layer * DINNER;
    const float* pb  = pro_b     + (size_t)layer * DINNER;

    u16* in_w_bf = in_w_bf0 + (size_t)layer * WBL;
    u16* pw_bf   = pw_bf0   + (size_t)layer * WBL;
    u16* wA_bf   = wA_bf0   + (size_t)layer * WBL;
    u16* wVT_bf  = wVT_bf0  + (size_t)layer * WBL;
    u16* ow_bf   = ow_bf0   + (size_t)layer * WBL;

    const float* xsrc = (layer == 0) ? in_x : xbuf;

    rmsnorm_k<<<LSEQ, blk, 0, stream>>>(xsrc, nw, xn_bf);

    // xz: wide tile, grid 384
    mgemmW_k<8><<<dim3(3072 / 128, LSEQ / 64), blk, 0, stream>>>(
        xn_bf, DMODEL, in_w_bf, DMODEL, xz_bf, 2 * DINNER, DMODEL, nullptr, nullptr, 0);

    conv_silu_k<<<dim3((LSEQ * DINNER) / 256, 2), blk, 0, stream>>>(
        xz_bf, cfw, cfb, cbw, cbb, xf_bf, xb_bf);

    thin_gemm_k<<<dim3(LSEQ / TG_R, TG_KS, 2), blk, 0, stream>>>(
        xf_bf, xb_bf, xfw, xbw, dbc_part);
    reduce_dbc_k<<<dim3((LSEQ * DBC) / 256, 2), blk, 0, stream>>>(
        dbc_part, dbcf, dbcb);

    delta_gemm_k<<<dim3(DINNER / BN, LSEQ / BM, 2), blk, 0, stream>>>(
        dbcf, dbcb, dfw, dbw, dfb, dbb, delf_bf, delb_bf);

    scan_a_k<<<dim3(DINNER / SCW, NQ - 1, 2), blk, 0, stream>>>(
        xf_bf, xb_bf, delf_bf, delb_bf, dbcf, dbcb, Af, Ab, qsP, qsQ);
    scan_c_k<<<dim3(DINNER / SCW, NQ, 2), blk, 0, stream>>>(
        xf_bf, xb_bf, delf_bf, delb_bf, dbcf, dbcb, Af, Ab, Df, Db, qsP, qsQ, ycat_bf);

    // ypro: 64x64 tile, grid 384
    mgemm_k<9><<<dim3(DINNER / 64, LSEQ / 64), blk, 0, stream>>>(
        ycat_bf, 2 * DINNER, pw_bf, 2 * DINNER, ypro_bf, DINNER, 2 * DINNER,
        pb, nullptr, 0);

    svgemm_k<<<640, blk, 0, stream>>>(wA_bf, ypro_bf, wVT_bf, Smat, vvT_bf);
    softmax_k<<<LSEQ, blk, 0, stream>>>(Smat, Smat_bf);

    // g: 64x64 tile, grid 384
    mgemm_k<56><<<dim3(DINNER / 64, LSEQ / 64), blk, 0, stream>>>(
        Smat_bf, LSEQ, vvT_bf, LSEQ, g_bf, DINNER, LSEQ,
        nullptr, (const float*)(xz_bf + DINNER), 2 * DINNER);

    // x_next: 32x64 tile -> grid (12, 32) = 384 blocks (was 192)
    float* target = (layer == NLAYER - 1) ? (float*)d_out : xbuf;
    mgemmH_k<4><<<dim3(DMODEL / 64, LSEQ / 32), blk, 0, stream>>>(
        g_bf, DINNER, ow_bf, DINNER, target, DMODEL, DINNER,
        nullptr, xsrc, DMODEL);
  }
}